// Round 6
// baseline (388.741 us; speedup 1.0000x reference)
//
#include <hip/hip_runtime.h>
#include <math.h>

#define NS 4096
#define NF 512
#define NB 16
#define NC 10
#define HSIZE 8192
#define HMASK 8191
#define HEMPTY 0xFFFFFFFFu
#define WS_XT_OFF 1024   // bytes reserved for counts at base of workspace

// ---------------- kernel 1 (fallback only): per-(b,c) class counts ----------------
__global__ void count_classes_kernel(const int* __restrict__ y, float* __restrict__ counts) {
    __shared__ int hist[NC];
    const int b = blockIdx.x;
    if (threadIdx.x < NC) hist[threadIdx.x] = 0;
    __syncthreads();
    for (int s = threadIdx.x; s < NS; s += blockDim.x)
        atomicAdd(&hist[y[b * NS + s]], 1);
    __syncthreads();
    if (threadIdx.x < NC) counts[b * NC + threadIdx.x] = (float)hist[threadIdx.x];
}

// ---------------- helpers ----------------
__device__ __forceinline__ float wave_reduce_add(float v) {
    #pragma unroll
    for (int off = 32; off > 0; off >>= 1) v += __shfl_down(v, off, 64);
    return v;
}
__device__ __forceinline__ float wave_reduce_max(float v) {
    #pragma unroll
    for (int off = 32; off > 0; off >>= 1) v = fmaxf(v, __shfl_down(v, off, 64));
    return v;
}

// ---------------- kernel T: tiled transpose X[b,s,f] -> XT[b,f,s] + class counts ---
// 64x64 tile per block, float4 on both sides, LDS [64][65] kills bank conflicts.
// The 16 blocks with (blockIdx.y==0 && blockIdx.z==0) also build counts[b][*].
__launch_bounds__(256)
__global__ void transpose_kernel(const float* __restrict__ X, float* __restrict__ XT,
                                 const int* __restrict__ y, float* __restrict__ counts) {
    __shared__ float t[64][65];
    __shared__ int hist[NC];
    const int b  = blockIdx.x;
    const int s0 = blockIdx.y * 64;
    const int f0 = blockIdx.z * 64;
    const int tid = threadIdx.x;

    const int fi = (tid & 15) * 4;     // 0..60
    const int si = tid >> 4;           // 0..15
    const float* Xb = X + ((size_t)b * NS + s0) * NF + f0;
    #pragma unroll
    for (int i = 0; i < 4; i++) {
        const int s = si + 16 * i;
        const float4 v = *(const float4*)(Xb + (size_t)s * NF + fi);
        t[s][fi + 0] = v.x; t[s][fi + 1] = v.y;
        t[s][fi + 2] = v.z; t[s][fi + 3] = v.w;
    }
    __syncthreads();

    const int sj = (tid & 15) * 4;
    const int fj = tid >> 4;
    float* XTb = XT + ((size_t)b * NF + f0) * NS + s0;
    #pragma unroll
    for (int i = 0; i < 4; i++) {
        const int f = fj + 16 * i;
        float4 v;
        v.x = t[sj + 0][f]; v.y = t[sj + 1][f];
        v.z = t[sj + 2][f]; v.w = t[sj + 3][f];
        *(float4*)(XTb + (size_t)f * NS + sj) = v;
    }

    if (blockIdx.y == 0 && blockIdx.z == 0) {      // block-uniform condition
        if (tid < NC) hist[tid] = 0;
        __syncthreads();
        const int4* yb = (const int4*)(y + (size_t)b * NS);
        #pragma unroll
        for (int i = 0; i < 4; i++) {              // 4096 ints = 1024 int4
            const int4 v = yb[i * 256 + tid];
            atomicAdd(&hist[v.x], 1); atomicAdd(&hist[v.y], 1);
            atomicAdd(&hist[v.z], 1); atomicAdd(&hist[v.w], 1);
        }
        __syncthreads();
        if (tid < NC) counts[b * NC + tid] = (float)hist[tid];
    }
}

// ---------------- kernel 2 (fast): fused stats + hash-unique + MLP on XT ----------
// ONE 512-THREAD workgroup per (b, f) column, 8 elements/thread.
// Rationale: the 32 KB hash caps blocks/CU at 4; with 8 waves/block that is
// 32 waves/CU (100% occupancy ceiling) vs 16 before -> DS/VMEM latency hidden
// by TLP instead of (repeatedly failed) ILP scheduling.
// LDS = exactly 32 KB; reduction buffers aliased into the hash after a barrier.
// launch_bounds(512,8): 8 waves/EU resident -> VGPR capped at 64.
__launch_bounds__(512, 8)
__global__ void fused_stats_mlp_xt(const float* __restrict__ XT,
                                   const int* __restrict__ y,
                                   const float* __restrict__ counts,
                                   const float* __restrict__ w1,
                                   const float* __restrict__ b1,
                                   const float* __restrict__ w2,
                                   const float* __restrict__ b2,
                                   float* __restrict__ out) {
    __shared__ __align__(16) unsigned int hash[HSIZE];   // 32 KB, multi-purpose

    const int w = blockIdx.x;
    const int g = (w & 7) * 1024 + (w >> 3);   // XCD swizzle, bijection over [0,8192)
    const int b = g >> 9;
    const int f = g & (NF - 1);
    const int tid = threadIdx.x;
    const int wave = tid >> 6, lane = tid & 63;

    // vectorized hash init: 4x ds_write_b128 per thread
    uint4* h4 = (uint4*)hash;
    const uint4 e4 = make_uint4(HEMPTY, HEMPTY, HEMPTY, HEMPTY);
    #pragma unroll
    for (int i = 0; i < HSIZE / 4 / 512; i++) h4[i * 512 + tid] = e4;
    __syncthreads();

    const float4* Xc4 = (const float4*)(XT + ((size_t)b * NF + f) * NS);
    const int4*   yp4 = (const int4*)(y + (size_t)b * NS);

    float sum = 0.f, sumsq = 0.f, sumabs = 0.f, maxabs = 0.f, nancnt = 0.f, uniq = 0.f;
    float csum[NC];
    #pragma unroll
    for (int c = 0; c < NC; c++) csum[c] = 0.f;

    // 2x float4 + 2x int4 upfront (8 elements/thread)
    float4 xv[2]; int4 yv[2];
    #pragma unroll
    for (int k = 0; k < 2; k++) {
        xv[k] = Xc4[k * 512 + tid];
        yv[k] = yp4[k * 512 + tid];
    }

    #pragma unroll
    for (int k = 0; k < 2; k++) {
        const float xe[4] = { xv[k].x, xv[k].y, xv[k].z, xv[k].w };
        const int   ye[4] = { yv[k].x, yv[k].y, yv[k].z, yv[k].w };
        #pragma unroll
        for (int j = 0; j < 4; j++) {
            float x = xe[j];
            if (x != x) { nancnt += 1.f; x = 0.f; }   // nan_to_num
            sum += x;
            sumsq = fmaf(x, x, sumsq);
            const float a = fabsf(x);
            sumabs += a;
            maxabs = fmaxf(maxabs, a);
            const int yc = ye[j];
            #pragma unroll
            for (int c = 0; c < NC; c++) csum[c] += (yc == c) ? x : 0.f;
            // distinct-value insert (value-equality: -0.0 == +0.0, NaN -> 0)
            unsigned int pat = __float_as_uint(x);
            if (pat == 0x80000000u) pat = 0u;
            unsigned int slot = (pat * 2654435761u) >> 19;   // top 13 bits
            for (;;) {
                const unsigned int old = atomicCAS(&hash[slot], HEMPTY, pat);
                if (old == HEMPTY) { uniq += 1.f; break; }   // first insertion
                if (old == pat) break;                        // duplicate
                slot = (slot + 1) & HMASK;                    // linear probe
            }
        }
    }

    __syncthreads();   // ALL hash CAS complete before re-aliasing the region

    // -------- block reduction + final stats (aliased into hash region) ----------
    float (*red)[16] = (float(*)[16])hash;     // floats [0,128)
    float* stats_s   = (float*)hash + 128;     // floats [128,134)
    float* h_s       = (float*)hash + 192;     // floats [192,256)

    sum    = wave_reduce_add(sum);
    sumsq  = wave_reduce_add(sumsq);
    sumabs = wave_reduce_add(sumabs);
    nancnt = wave_reduce_add(nancnt);
    uniq   = wave_reduce_add(uniq);
    maxabs = wave_reduce_max(maxabs);
    #pragma unroll
    for (int c = 0; c < NC; c++) csum[c] = wave_reduce_add(csum[c]);

    if (lane == 0) {
        red[wave][0] = sum;    red[wave][1] = sumsq; red[wave][2] = sumabs;
        red[wave][3] = nancnt; red[wave][4] = uniq;  red[wave][5] = maxabs;
        #pragma unroll
        for (int c = 0; c < NC; c++) red[wave][6 + c] = csum[c];
    }
    __syncthreads();

    if (tid == 0) {
        float t[16];
        #pragma unroll
        for (int v = 0; v < 16; v++) t[v] = red[0][v];
        #pragma unroll
        for (int wv = 1; wv < 8; wv++) {
            #pragma unroll
            for (int v = 0; v < 16; v++) {
                if (v == 5) t[v] = fmaxf(t[v], red[wv][v]);
                else        t[v] += red[wv][v];
            }
        }
        const float invS = 1.f / (float)NS;
        const float gmean    = t[0] * invS;
        const float variance = fmaxf(t[1] * invS - gmean * gmean, 0.f);  // biased
        const float mean_abs = t[2] * invS;
        const float missing  = t[3] * invS;
        const float n_unique = t[4];
        const float max_abs  = t[5];
        float between = 0.f;
        #pragma unroll
        for (int c = 0; c < NC; c++) {
            const float cnt = counts[b * NC + c];
            const float cm  = t[6 + c] / fmaxf(cnt, 1.f);
            const float d   = cm - gmean;
            between += cnt * d * d;
        }
        between *= invS;                                   // counts.sum() == NS
        const float target = between / fmaxf(variance, 1e-6f);
        float st[6] = { target, missing, n_unique * invS, variance, mean_abs, max_abs };
        #pragma unroll
        for (int i = 0; i < 6; i++) {
            float v = st[i];
            if (!(fabsf(v) < INFINITY)) v = 0.f;           // nan_to_num
            stats_s[i] = v;
        }
    }
    __syncthreads();

    // MLP epilogue: 6 -> 64 (exact GELU) -> 128
    if (tid < 64) {
        float z = b1[tid];
        #pragma unroll
        for (int i = 0; i < 6; i++) z = fmaf(stats_s[i], w1[i * 64 + tid], z);
        h_s[tid] = 0.5f * z * (1.f + erff(z * 0.70710678118654752440f));
    }
    __syncthreads();
    if (tid < 128) {
        float o = b2[tid];
        #pragma unroll
        for (int j = 0; j < 64; j++) o = fmaf(h_s[j], w2[j * 128 + tid], o);
        out[(size_t)g * 128 + tid] = o;
    }
}

// ---------------- kernel 2 (fallback): round-0 strided version ----------------
__launch_bounds__(256)
__global__ void fused_stats_mlp_kernel(const float* __restrict__ X,
                                       const int* __restrict__ y,
                                       const float* __restrict__ counts,
                                       const float* __restrict__ w1,
                                       const float* __restrict__ b1,
                                       const float* __restrict__ w2,
                                       const float* __restrict__ b2,
                                       float* __restrict__ out) {
    __shared__ unsigned int hash[HSIZE];
    __shared__ float red[4][16];
    __shared__ float stats_s[6];
    __shared__ float h_s[64];

    const int w = blockIdx.x;
    const int g = (w & 7) * 1024 + (w >> 3);
    const int b = g >> 9;
    const int f = g & (NF - 1);
    const int tid = threadIdx.x;

    #pragma unroll
    for (int i = 0; i < HSIZE / 256; i++) hash[tid + i * 256] = HEMPTY;
    __syncthreads();

    const float* Xp = X + (size_t)b * NS * NF + f;
    const int*   yp = y + b * NS;

    float sum = 0.f, sumsq = 0.f, sumabs = 0.f, maxabs = 0.f, nancnt = 0.f, uniq = 0.f;
    float csum[NC];
    #pragma unroll
    for (int c = 0; c < NC; c++) csum[c] = 0.f;

    #pragma unroll
    for (int k0 = 0; k0 < 16; k0 += 8) {
        float xv[8]; int yv[8];
        #pragma unroll
        for (int k = 0; k < 8; k++) {
            const int s = (k0 + k) * 256 + tid;
            xv[k] = Xp[(size_t)s * NF];
            yv[k] = yp[s];
        }
        #pragma unroll
        for (int k = 0; k < 8; k++) {
            float x = xv[k];
            if (x != x) { nancnt += 1.f; x = 0.f; }
            sum += x;
            sumsq = fmaf(x, x, sumsq);
            const float a = fabsf(x);
            sumabs += a;
            maxabs = fmaxf(maxabs, a);
            const int yc = yv[k];
            #pragma unroll
            for (int c = 0; c < NC; c++) csum[c] += (yc == c) ? x : 0.f;
            unsigned int pat = __float_as_uint(x);
            if (pat == 0x80000000u) pat = 0u;
            unsigned int slot = (pat * 2654435761u) >> 19;
            for (;;) {
                const unsigned int old = atomicCAS(&hash[slot], HEMPTY, pat);
                if (old == HEMPTY) { uniq += 1.f; break; }
                if (old == pat) break;
                slot = (slot + 1) & HMASK;
            }
        }
    }

    sum    = wave_reduce_add(sum);
    sumsq  = wave_reduce_add(sumsq);
    sumabs = wave_reduce_add(sumabs);
    nancnt = wave_reduce_add(nancnt);
    uniq   = wave_reduce_add(uniq);
    maxabs = wave_reduce_max(maxabs);
    #pragma unroll
    for (int c = 0; c < NC; c++) csum[c] = wave_reduce_add(csum[c]);

    const int wave = tid >> 6, lane = tid & 63;
    if (lane == 0) {
        red[wave][0] = sum;    red[wave][1] = sumsq; red[wave][2] = sumabs;
        red[wave][3] = nancnt; red[wave][4] = uniq;  red[wave][5] = maxabs;
        #pragma unroll
        for (int c = 0; c < NC; c++) red[wave][6 + c] = csum[c];
    }
    __syncthreads();

    if (tid == 0) {
        float t[16];
        #pragma unroll
        for (int v = 0; v < 16; v++) t[v] = red[0][v];
        #pragma unroll
        for (int wv = 1; wv < 4; wv++) {
            #pragma unroll
            for (int v = 0; v < 16; v++) {
                if (v == 5) t[v] = fmaxf(t[v], red[wv][v]);
                else        t[v] += red[wv][v];
            }
        }
        const float invS = 1.f / (float)NS;
        const float gmean    = t[0] * invS;
        const float variance = fmaxf(t[1] * invS - gmean * gmean, 0.f);
        const float mean_abs = t[2] * invS;
        const float missing  = t[3] * invS;
        const float n_unique = t[4];
        const float max_abs  = t[5];
        float between = 0.f;
        #pragma unroll
        for (int c = 0; c < NC; c++) {
            const float cnt = counts[b * NC + c];
            const float cm  = t[6 + c] / fmaxf(cnt, 1.f);
            const float d   = cm - gmean;
            between += cnt * d * d;
        }
        between *= invS;
        const float target = between / fmaxf(variance, 1e-6f);
        float st[6] = { target, missing, n_unique * invS, variance, mean_abs, max_abs };
        #pragma unroll
        for (int i = 0; i < 6; i++) {
            float v = st[i];
            if (!(fabsf(v) < INFINITY)) v = 0.f;
            stats_s[i] = v;
        }
    }
    __syncthreads();

    if (tid < 64) {
        float z = b1[tid];
        #pragma unroll
        for (int i = 0; i < 6; i++) z = fmaf(stats_s[i], w1[i * 64 + tid], z);
        h_s[tid] = 0.5f * z * (1.f + erff(z * 0.70710678118654752440f));
    }
    __syncthreads();
    if (tid < 128) {
        float o = b2[tid];
        #pragma unroll
        for (int j = 0; j < 64; j++) o = fmaf(h_s[j], w2[j * 128 + tid], o);
        out[(size_t)g * 128 + tid] = o;
    }
}

extern "C" void kernel_launch(void* const* d_in, const int* in_sizes, int n_in,
                              void* d_out, int out_size, void* d_ws, size_t ws_size,
                              hipStream_t stream) {
    const float* X  = (const float*)d_in[0];
    const int*   y  = (const int*)d_in[1];
    const float* w1 = (const float*)d_in[2];
    const float* b1 = (const float*)d_in[3];
    const float* w2 = (const float*)d_in[4];
    const float* b2 = (const float*)d_in[5];
    float* out    = (float*)d_out;
    float* counts = (float*)d_ws;          // 16*10 floats at workspace base

    const size_t xt_bytes = (size_t)NB * NF * NS * sizeof(float);   // 128 MB
    if (ws_size >= xt_bytes + WS_XT_OFF) {
        float* XT = (float*)((char*)d_ws + WS_XT_OFF);
        transpose_kernel<<<dim3(NB, NS / 64, NF / 64), 256, 0, stream>>>(X, XT, y, counts);
        fused_stats_mlp_xt<<<NB * NF, 512, 0, stream>>>(XT, y, counts, w1, b1, w2, b2, out);
    } else {
        // workspace too small: proven strided path (round-0 structure)
        count_classes_kernel<<<NB, 256, 0, stream>>>(y, counts);
        fused_stats_mlp_kernel<<<NB * NF, 256, 0, stream>>>(X, y, counts, w1, b1, w2, b2, out);
    }
}

// Round 7
// 373.078 us; speedup vs baseline: 1.0420x; 1.0420x over previous
//
#include <hip/hip_runtime.h>
#include <math.h>

#define NS 4096
#define NF 512
#define NB 16
#define NC 10
#define HSIZE 8192
#define HMASK 8191
#define HEMPTY 0xFFFFFFFFu
#define WS_XT_OFF 1024   // bytes reserved for counts at base of workspace

// ---------------- kernel 1 (fallback only): per-(b,c) class counts ----------------
__global__ void count_classes_kernel(const int* __restrict__ y, float* __restrict__ counts) {
    __shared__ int hist[NC];
    const int b = blockIdx.x;
    if (threadIdx.x < NC) hist[threadIdx.x] = 0;
    __syncthreads();
    for (int s = threadIdx.x; s < NS; s += blockDim.x)
        atomicAdd(&hist[y[b * NS + s]], 1);
    __syncthreads();
    if (threadIdx.x < NC) counts[b * NC + threadIdx.x] = (float)hist[threadIdx.x];
}

// ---------------- helpers ----------------
__device__ __forceinline__ float wave_reduce_add(float v) {
    #pragma unroll
    for (int off = 32; off > 0; off >>= 1) v += __shfl_down(v, off, 64);
    return v;
}
__device__ __forceinline__ float wave_reduce_max(float v) {
    #pragma unroll
    for (int off = 32; off > 0; off >>= 1) v = fmaxf(v, __shfl_down(v, off, 64));
    return v;
}

__device__ __forceinline__ unsigned int pat_of(float x) {
    if (x != x) x = 0.f;                       // nan_to_num for the hash
    unsigned int p = __float_as_uint(x);
    return (p == 0x80000000u) ? 0u : p;        // -0.0 == +0.0 value semantics
}

// resolve one CAS result; rare collision path continues linear probing
__device__ __forceinline__ float resolve1(unsigned int* hash,
                                          unsigned int s, unsigned int p, unsigned int o) {
    if (o == HEMPTY) return 1.f;               // first insertion of this value
    if (o == p)      return 0.f;               // duplicate
    for (;;) {
        s = (s + 1) & HMASK;
        const unsigned int oo = atomicCAS(&hash[s], HEMPTY, p);
        if (oo == HEMPTY) return 1.f;
        if (oo == p)      return 0.f;
    }
}

// 8 elements: prep, issue 8 independent CAS (named scalars -> no scratch,
// back-to-back DS issue, one latency exposure), then resolve.
__device__ __forceinline__ float hash8(unsigned int* hash, const float4 u, const float4 v) {
    const unsigned int p0 = pat_of(u.x), p1 = pat_of(u.y), p2 = pat_of(u.z), p3 = pat_of(u.w);
    const unsigned int p4 = pat_of(v.x), p5 = pat_of(v.y), p6 = pat_of(v.z), p7 = pat_of(v.w);
    const unsigned int s0 = (p0 * 2654435761u) >> 19, s1 = (p1 * 2654435761u) >> 19;
    const unsigned int s2 = (p2 * 2654435761u) >> 19, s3 = (p3 * 2654435761u) >> 19;
    const unsigned int s4 = (p4 * 2654435761u) >> 19, s5 = (p5 * 2654435761u) >> 19;
    const unsigned int s6 = (p6 * 2654435761u) >> 19, s7 = (p7 * 2654435761u) >> 19;
    const unsigned int o0 = atomicCAS(&hash[s0], HEMPTY, p0);
    const unsigned int o1 = atomicCAS(&hash[s1], HEMPTY, p1);
    const unsigned int o2 = atomicCAS(&hash[s2], HEMPTY, p2);
    const unsigned int o3 = atomicCAS(&hash[s3], HEMPTY, p3);
    const unsigned int o4 = atomicCAS(&hash[s4], HEMPTY, p4);
    const unsigned int o5 = atomicCAS(&hash[s5], HEMPTY, p5);
    const unsigned int o6 = atomicCAS(&hash[s6], HEMPTY, p6);
    const unsigned int o7 = atomicCAS(&hash[s7], HEMPTY, p7);
    float u8 = 0.f;
    u8 += resolve1(hash, s0, p0, o0);
    u8 += resolve1(hash, s1, p1, o1);
    u8 += resolve1(hash, s2, p2, o2);
    u8 += resolve1(hash, s3, p3, o3);
    u8 += resolve1(hash, s4, p4, o4);
    u8 += resolve1(hash, s5, p5, o5);
    u8 += resolve1(hash, s6, p6, o6);
    u8 += resolve1(hash, s7, p7, o7);
    return u8;
}

// ---------------- kernel T: tiled transpose X[b,s,f] -> XT[b,f,s] + class counts ---
__launch_bounds__(256)
__global__ void transpose_kernel(const float* __restrict__ X, float* __restrict__ XT,
                                 const int* __restrict__ y, float* __restrict__ counts) {
    __shared__ float t[64][65];
    __shared__ int hist[NC];
    const int b  = blockIdx.x;
    const int s0 = blockIdx.y * 64;
    const int f0 = blockIdx.z * 64;
    const int tid = threadIdx.x;

    const int fi = (tid & 15) * 4;     // 0..60
    const int si = tid >> 4;           // 0..15
    const float* Xb = X + ((size_t)b * NS + s0) * NF + f0;
    #pragma unroll
    for (int i = 0; i < 4; i++) {
        const int s = si + 16 * i;
        const float4 v = *(const float4*)(Xb + (size_t)s * NF + fi);
        t[s][fi + 0] = v.x; t[s][fi + 1] = v.y;
        t[s][fi + 2] = v.z; t[s][fi + 3] = v.w;
    }
    __syncthreads();

    const int sj = (tid & 15) * 4;
    const int fj = tid >> 4;
    float* XTb = XT + ((size_t)b * NF + f0) * NS + s0;
    #pragma unroll
    for (int i = 0; i < 4; i++) {
        const int f = fj + 16 * i;
        float4 v;
        v.x = t[sj + 0][f]; v.y = t[sj + 1][f];
        v.z = t[sj + 2][f]; v.w = t[sj + 3][f];
        *(float4*)(XTb + (size_t)f * NS + sj) = v;
    }

    if (blockIdx.y == 0 && blockIdx.z == 0) {      // block-uniform condition
        if (tid < NC) hist[tid] = 0;
        __syncthreads();
        const int4* yb = (const int4*)(y + (size_t)b * NS);
        #pragma unroll
        for (int i = 0; i < 4; i++) {              // 4096 ints = 1024 int4
            const int4 v = yb[i * 256 + tid];
            atomicAdd(&hist[v.x], 1); atomicAdd(&hist[v.y], 1);
            atomicAdd(&hist[v.z], 1); atomicAdd(&hist[v.w], 1);
        }
        __syncthreads();
        if (tid < NC) counts[b * NC + tid] = (float)hist[tid];
    }
}

// ---------------- kernel 2 (fast): wave-specialized stats + hash + MLP on XT ------
// ONE 512-THREAD workgroup per (b, f) column.
// Waves 0-3: ALL streaming stats (pure VALU+VMEM, zero DS ops, never stall on DS).
// Waves 4-7: ALL hash inserts (batched 8-wide CAS, minimal VALU).
// Rationale (R6 evidence): interleaving stats and CAS per-thread serializes on the
// per-CU DS pipe; specialization lets the CU overlap VALU waves with DS waves
// (m114 co-scheduling), turning sum into max. Both halves read the column
// (2nd read is L3-resident XT, ~free).
__launch_bounds__(512, 8)
__global__ void fused_stats_mlp_xt(const float* __restrict__ XT,
                                   const int* __restrict__ y,
                                   const float* __restrict__ counts,
                                   const float* __restrict__ w1,
                                   const float* __restrict__ b1,
                                   const float* __restrict__ w2,
                                   const float* __restrict__ b2,
                                   float* __restrict__ out) {
    __shared__ __align__(16) unsigned int hash[HSIZE];   // 32 KB, multi-purpose

    const int w = blockIdx.x;
    const int g = (w & 7) * 1024 + (w >> 3);   // XCD swizzle, bijection over [0,8192)
    const int b = g >> 9;
    const int f = g & (NF - 1);
    const int tid = threadIdx.x;
    const int wave = tid >> 6, lane = tid & 63;

    // vectorized hash init: 4x ds_write_b128 per thread
    uint4* h4 = (uint4*)hash;
    const uint4 e4 = make_uint4(HEMPTY, HEMPTY, HEMPTY, HEMPTY);
    #pragma unroll
    for (int i = 0; i < HSIZE / 4 / 512; i++) h4[i * 512 + tid] = e4;
    __syncthreads();

    const float4* Xc4 = (const float4*)(XT + ((size_t)b * NF + f) * NS);
    const int4*   yp4 = (const int4*)(y + (size_t)b * NS);

    float sum = 0.f, sumsq = 0.f, sumabs = 0.f, maxabs = 0.f, nancnt = 0.f, uniq = 0.f;
    float csum[NC];
    #pragma unroll
    for (int c = 0; c < NC; c++) csum[c] = 0.f;

    if (wave < 4) {
        // ---------------- stats role: 16 elements/thread, no DS ops --------------
        const int ts = tid;                        // 0..255
        float4 xv[4]; int4 yv[4];
        #pragma unroll
        for (int k = 0; k < 4; k++) {
            xv[k] = Xc4[k * 256 + ts];
            yv[k] = yp4[k * 256 + ts];
        }
        #pragma unroll
        for (int k = 0; k < 4; k++) {
            const float xe[4] = { xv[k].x, xv[k].y, xv[k].z, xv[k].w };
            const int   ye[4] = { yv[k].x, yv[k].y, yv[k].z, yv[k].w };
            #pragma unroll
            for (int j = 0; j < 4; j++) {
                float x = xe[j];
                if (x != x) { nancnt += 1.f; x = 0.f; }   // nan_to_num
                sum += x;
                sumsq = fmaf(x, x, sumsq);
                const float a = fabsf(x);
                sumabs += a;
                maxabs = fmaxf(maxabs, a);
                const int yc = ye[j];
                #pragma unroll
                for (int c = 0; c < NC; c++) csum[c] += (yc == c) ? x : 0.f;
            }
        }
    } else {
        // ---------------- hash role: 16 elements/thread, batched CAS -------------
        const int th = tid - 256;                  // 0..255
        const float4 xa = Xc4[th];
        const float4 xb = Xc4[256 + th];
        const float4 xc = Xc4[512 + th];
        const float4 xd = Xc4[768 + th];
        uniq += hash8(hash, xa, xb);
        uniq += hash8(hash, xc, xd);
    }

    __syncthreads();   // ALL hash CAS complete before re-aliasing the region

    // -------- block reduction + final stats (aliased into hash region) ----------
    float (*red)[16] = (float(*)[16])hash;     // floats [0,128)
    float* stats_s   = (float*)hash + 128;     // floats [128,134)
    float* h_s       = (float*)hash + 192;     // floats [192,256)

    sum    = wave_reduce_add(sum);
    sumsq  = wave_reduce_add(sumsq);
    sumabs = wave_reduce_add(sumabs);
    nancnt = wave_reduce_add(nancnt);
    uniq   = wave_reduce_add(uniq);
    maxabs = wave_reduce_max(maxabs);
    #pragma unroll
    for (int c = 0; c < NC; c++) csum[c] = wave_reduce_add(csum[c]);

    if (lane == 0) {
        red[wave][0] = sum;    red[wave][1] = sumsq; red[wave][2] = sumabs;
        red[wave][3] = nancnt; red[wave][4] = uniq;  red[wave][5] = maxabs;
        #pragma unroll
        for (int c = 0; c < NC; c++) red[wave][6 + c] = csum[c];
    }
    __syncthreads();

    if (tid == 0) {
        float t[16];
        #pragma unroll
        for (int v = 0; v < 16; v++) t[v] = red[0][v];
        #pragma unroll
        for (int wv = 1; wv < 8; wv++) {
            #pragma unroll
            for (int v = 0; v < 16; v++) {
                if (v == 5) t[v] = fmaxf(t[v], red[wv][v]);
                else        t[v] += red[wv][v];
            }
        }
        const float invS = 1.f / (float)NS;
        const float gmean    = t[0] * invS;
        const float variance = fmaxf(t[1] * invS - gmean * gmean, 0.f);  // biased
        const float mean_abs = t[2] * invS;
        const float missing  = t[3] * invS;
        const float n_unique = t[4];
        const float max_abs  = t[5];
        float between = 0.f;
        #pragma unroll
        for (int c = 0; c < NC; c++) {
            const float cnt = counts[b * NC + c];
            const float cm  = t[6 + c] / fmaxf(cnt, 1.f);
            const float d   = cm - gmean;
            between += cnt * d * d;
        }
        between *= invS;                                   // counts.sum() == NS
        const float target = between / fmaxf(variance, 1e-6f);
        float st[6] = { target, missing, n_unique * invS, variance, mean_abs, max_abs };
        #pragma unroll
        for (int i = 0; i < 6; i++) {
            float v = st[i];
            if (!(fabsf(v) < INFINITY)) v = 0.f;           // nan_to_num
            stats_s[i] = v;
        }
    }
    __syncthreads();

    // MLP epilogue: 6 -> 64 (exact GELU) -> 128
    if (tid < 64) {
        float z = b1[tid];
        #pragma unroll
        for (int i = 0; i < 6; i++) z = fmaf(stats_s[i], w1[i * 64 + tid], z);
        h_s[tid] = 0.5f * z * (1.f + erff(z * 0.70710678118654752440f));
    }
    __syncthreads();
    if (tid < 128) {
        float o = b2[tid];
        #pragma unroll
        for (int j = 0; j < 64; j++) o = fmaf(h_s[j], w2[j * 128 + tid], o);
        out[(size_t)g * 128 + tid] = o;
    }
}

// ---------------- kernel 2 (fallback): round-0 strided version ----------------
__launch_bounds__(256)
__global__ void fused_stats_mlp_kernel(const float* __restrict__ X,
                                       const int* __restrict__ y,
                                       const float* __restrict__ counts,
                                       const float* __restrict__ w1,
                                       const float* __restrict__ b1,
                                       const float* __restrict__ w2,
                                       const float* __restrict__ b2,
                                       float* __restrict__ out) {
    __shared__ unsigned int hash[HSIZE];
    __shared__ float red[4][16];
    __shared__ float stats_s[6];
    __shared__ float h_s[64];

    const int w = blockIdx.x;
    const int g = (w & 7) * 1024 + (w >> 3);
    const int b = g >> 9;
    const int f = g & (NF - 1);
    const int tid = threadIdx.x;

    #pragma unroll
    for (int i = 0; i < HSIZE / 256; i++) hash[tid + i * 256] = HEMPTY;
    __syncthreads();

    const float* Xp = X + (size_t)b * NS * NF + f;
    const int*   yp = y + b * NS;

    float sum = 0.f, sumsq = 0.f, sumabs = 0.f, maxabs = 0.f, nancnt = 0.f, uniq = 0.f;
    float csum[NC];
    #pragma unroll
    for (int c = 0; c < NC; c++) csum[c] = 0.f;

    #pragma unroll
    for (int k0 = 0; k0 < 16; k0 += 8) {
        float xv[8]; int yv[8];
        #pragma unroll
        for (int k = 0; k < 8; k++) {
            const int s = (k0 + k) * 256 + tid;
            xv[k] = Xp[(size_t)s * NF];
            yv[k] = yp[s];
        }
        #pragma unroll
        for (int k = 0; k < 8; k++) {
            float x = xv[k];
            if (x != x) { nancnt += 1.f; x = 0.f; }
            sum += x;
            sumsq = fmaf(x, x, sumsq);
            const float a = fabsf(x);
            sumabs += a;
            maxabs = fmaxf(maxabs, a);
            const int yc = yv[k];
            #pragma unroll
            for (int c = 0; c < NC; c++) csum[c] += (yc == c) ? x : 0.f;
            unsigned int pat = __float_as_uint(x);
            if (pat == 0x80000000u) pat = 0u;
            unsigned int slot = (pat * 2654435761u) >> 19;
            for (;;) {
                const unsigned int old = atomicCAS(&hash[slot], HEMPTY, pat);
                if (old == HEMPTY) { uniq += 1.f; break; }
                if (old == pat) break;
                slot = (slot + 1) & HMASK;
            }
        }
    }

    sum    = wave_reduce_add(sum);
    sumsq  = wave_reduce_add(sumsq);
    sumabs = wave_reduce_add(sumabs);
    nancnt = wave_reduce_add(nancnt);
    uniq   = wave_reduce_add(uniq);
    maxabs = wave_reduce_max(maxabs);
    #pragma unroll
    for (int c = 0; c < NC; c++) csum[c] = wave_reduce_add(csum[c]);

    const int wave = tid >> 6, lane = tid & 63;
    if (lane == 0) {
        red[wave][0] = sum;    red[wave][1] = sumsq; red[wave][2] = sumabs;
        red[wave][3] = nancnt; red[wave][4] = uniq;  red[wave][5] = maxabs;
        #pragma unroll
        for (int c = 0; c < NC; c++) red[wave][6 + c] = csum[c];
    }
    __syncthreads();

    if (tid == 0) {
        float t[16];
        #pragma unroll
        for (int v = 0; v < 16; v++) t[v] = red[0][v];
        #pragma unroll
        for (int wv = 1; wv < 4; wv++) {
            #pragma unroll
            for (int v = 0; v < 16; v++) {
                if (v == 5) t[v] = fmaxf(t[v], red[wv][v]);
                else        t[v] += red[wv][v];
            }
        }
        const float invS = 1.f / (float)NS;
        const float gmean    = t[0] * invS;
        const float variance = fmaxf(t[1] * invS - gmean * gmean, 0.f);
        const float mean_abs = t[2] * invS;
        const float missing  = t[3] * invS;
        const float n_unique = t[4];
        const float max_abs  = t[5];
        float between = 0.f;
        #pragma unroll
        for (int c = 0; c < NC; c++) {
            const float cnt = counts[b * NC + c];
            const float cm  = t[6 + c] / fmaxf(cnt, 1.f);
            const float d   = cm - gmean;
            between += cnt * d * d;
        }
        between *= invS;
        const float target = between / fmaxf(variance, 1e-6f);
        float st[6] = { target, missing, n_unique * invS, variance, mean_abs, max_abs };
        #pragma unroll
        for (int i = 0; i < 6; i++) {
            float v = st[i];
            if (!(fabsf(v) < INFINITY)) v = 0.f;
            stats_s[i] = v;
        }
    }
    __syncthreads();

    if (tid < 64) {
        float z = b1[tid];
        #pragma unroll
        for (int i = 0; i < 6; i++) z = fmaf(stats_s[i], w1[i * 64 + tid], z);
        h_s[tid] = 0.5f * z * (1.f + erff(z * 0.70710678118654752440f));
    }
    __syncthreads();
    if (tid < 128) {
        float o = b2[tid];
        #pragma unroll
        for (int j = 0; j < 64; j++) o = fmaf(h_s[j], w2[j * 128 + tid], o);
        out[(size_t)g * 128 + tid] = o;
    }
}

extern "C" void kernel_launch(void* const* d_in, const int* in_sizes, int n_in,
                              void* d_out, int out_size, void* d_ws, size_t ws_size,
                              hipStream_t stream) {
    const float* X  = (const float*)d_in[0];
    const int*   y  = (const int*)d_in[1];
    const float* w1 = (const float*)d_in[2];
    const float* b1 = (const float*)d_in[3];
    const float* w2 = (const float*)d_in[4];
    const float* b2 = (const float*)d_in[5];
    float* out    = (float*)d_out;
    float* counts = (float*)d_ws;          // 16*10 floats at workspace base

    const size_t xt_bytes = (size_t)NB * NF * NS * sizeof(float);   // 128 MB
    if (ws_size >= xt_bytes + WS_XT_OFF) {
        float* XT = (float*)((char*)d_ws + WS_XT_OFF);
        transpose_kernel<<<dim3(NB, NS / 64, NF / 64), 256, 0, stream>>>(X, XT, y, counts);
        fused_stats_mlp_xt<<<NB * NF, 512, 0, stream>>>(XT, y, counts, w1, b1, w2, b2, out);
    } else {
        // workspace too small: proven strided path (round-0 structure)
        count_classes_kernel<<<NB, 256, 0, stream>>>(y, counts);
        fused_stats_mlp_kernel<<<NB * NF, 256, 0, stream>>>(X, y, counts, w1, b1, w2, b2, out);
    }
}

// Round 8
// 348.555 us; speedup vs baseline: 1.1153x; 1.0704x over previous
//
#include <hip/hip_runtime.h>
#include <math.h>

#define NS 4096
#define NF 512
#define NB 16
#define NC 10
#define HSIZE 8192
#define HMASK 8191
#define HEMPTY 0xFFFFFFFFu
#define WS_XT_OFF 1024   // bytes reserved for counts at base of workspace

// ---------------- kernel 1 (fallback only): per-(b,c) class counts ----------------
__global__ void count_classes_kernel(const int* __restrict__ y, float* __restrict__ counts) {
    __shared__ int hist[NC];
    const int b = blockIdx.x;
    if (threadIdx.x < NC) hist[threadIdx.x] = 0;
    __syncthreads();
    for (int s = threadIdx.x; s < NS; s += blockDim.x)
        atomicAdd(&hist[y[b * NS + s]], 1);
    __syncthreads();
    if (threadIdx.x < NC) counts[b * NC + threadIdx.x] = (float)hist[threadIdx.x];
}

// ---------------- helpers ----------------
__device__ __forceinline__ float wave_reduce_add(float v) {
    #pragma unroll
    for (int off = 32; off > 0; off >>= 1) v += __shfl_down(v, off, 64);
    return v;
}
__device__ __forceinline__ float wave_reduce_max(float v) {
    #pragma unroll
    for (int off = 32; off > 0; off >>= 1) v = fmaxf(v, __shfl_down(v, off, 64));
    return v;
}

__device__ __forceinline__ unsigned int pat_of(float x) {
    if (x != x) x = 0.f;                       // nan_to_num for the hash
    unsigned int p = __float_as_uint(x);
    return (p == 0x80000000u) ? 0u : p;        // -0.0 == +0.0 value semantics
}

// resolve one CAS result; rare collision path continues linear probing
__device__ __forceinline__ float resolve1(unsigned int* hash,
                                          unsigned int s, unsigned int p, unsigned int o) {
    if (o == HEMPTY) return 1.f;               // first insertion of this value
    if (o == p)      return 0.f;               // duplicate
    for (;;) {
        s = (s + 1) & HMASK;
        const unsigned int oo = atomicCAS(&hash[s], HEMPTY, p);
        if (oo == HEMPTY) return 1.f;
        if (oo == p)      return 0.f;
    }
}

// 8 elements: prep, issue 8 independent CAS (named scalars -> no scratch,
// back-to-back DS issue, one latency exposure), then resolve.
__device__ __forceinline__ float hash8(unsigned int* hash, const float4 u, const float4 v) {
    const unsigned int p0 = pat_of(u.x), p1 = pat_of(u.y), p2 = pat_of(u.z), p3 = pat_of(u.w);
    const unsigned int p4 = pat_of(v.x), p5 = pat_of(v.y), p6 = pat_of(v.z), p7 = pat_of(v.w);
    const unsigned int s0 = (p0 * 2654435761u) >> 19, s1 = (p1 * 2654435761u) >> 19;
    const unsigned int s2 = (p2 * 2654435761u) >> 19, s3 = (p3 * 2654435761u) >> 19;
    const unsigned int s4 = (p4 * 2654435761u) >> 19, s5 = (p5 * 2654435761u) >> 19;
    const unsigned int s6 = (p6 * 2654435761u) >> 19, s7 = (p7 * 2654435761u) >> 19;
    const unsigned int o0 = atomicCAS(&hash[s0], HEMPTY, p0);
    const unsigned int o1 = atomicCAS(&hash[s1], HEMPTY, p1);
    const unsigned int o2 = atomicCAS(&hash[s2], HEMPTY, p2);
    const unsigned int o3 = atomicCAS(&hash[s3], HEMPTY, p3);
    const unsigned int o4 = atomicCAS(&hash[s4], HEMPTY, p4);
    const unsigned int o5 = atomicCAS(&hash[s5], HEMPTY, p5);
    const unsigned int o6 = atomicCAS(&hash[s6], HEMPTY, p6);
    const unsigned int o7 = atomicCAS(&hash[s7], HEMPTY, p7);
    float u8 = 0.f;
    u8 += resolve1(hash, s0, p0, o0);
    u8 += resolve1(hash, s1, p1, o1);
    u8 += resolve1(hash, s2, p2, o2);
    u8 += resolve1(hash, s3, p3, o3);
    u8 += resolve1(hash, s4, p4, o4);
    u8 += resolve1(hash, s5, p5, o5);
    u8 += resolve1(hash, s6, p6, o6);
    u8 += resolve1(hash, s7, p7, o7);
    return u8;
}

// ---------------- kernel T: tiled transpose X[b,s,f] -> XT[b,f,s] + class counts ---
__launch_bounds__(256)
__global__ void transpose_kernel(const float* __restrict__ X, float* __restrict__ XT,
                                 const int* __restrict__ y, float* __restrict__ counts) {
    __shared__ float t[64][65];
    __shared__ int hist[NC];
    const int b  = blockIdx.x;
    const int s0 = blockIdx.y * 64;
    const int f0 = blockIdx.z * 64;
    const int tid = threadIdx.x;

    const int fi = (tid & 15) * 4;     // 0..60
    const int si = tid >> 4;           // 0..15
    const float* Xb = X + ((size_t)b * NS + s0) * NF + f0;
    #pragma unroll
    for (int i = 0; i < 4; i++) {
        const int s = si + 16 * i;
        const float4 v = *(const float4*)(Xb + (size_t)s * NF + fi);
        t[s][fi + 0] = v.x; t[s][fi + 1] = v.y;
        t[s][fi + 2] = v.z; t[s][fi + 3] = v.w;
    }
    __syncthreads();

    const int sj = (tid & 15) * 4;
    const int fj = tid >> 4;
    float* XTb = XT + ((size_t)b * NF + f0) * NS + s0;
    #pragma unroll
    for (int i = 0; i < 4; i++) {
        const int f = fj + 16 * i;
        float4 v;
        v.x = t[sj + 0][f]; v.y = t[sj + 1][f];
        v.z = t[sj + 2][f]; v.w = t[sj + 3][f];
        *(float4*)(XTb + (size_t)f * NS + sj) = v;
    }

    if (blockIdx.y == 0 && blockIdx.z == 0) {      // block-uniform condition
        if (tid < NC) hist[tid] = 0;
        __syncthreads();
        const int4* yb = (const int4*)(y + (size_t)b * NS);
        #pragma unroll
        for (int i = 0; i < 4; i++) {              // 4096 ints = 1024 int4
            const int4 v = yb[i * 256 + tid];
            atomicAdd(&hist[v.x], 1); atomicAdd(&hist[v.y], 1);
            atomicAdd(&hist[v.z], 1); atomicAdd(&hist[v.w], 1);
        }
        __syncthreads();
        if (tid < NC) counts[b * NC + tid] = (float)hist[tid];
    }
}

// ---------------- kernel 2 (fast): wave-specialized stats + hash + MLP on XT ------
// ONE 512-THREAD workgroup per (b, f) column.
// Waves 0-3: ALL streaming stats (pure VALU+VMEM, zero DS ops in main phase).
// Waves 4-7: ALL hash inserts (batched 8-wide CAS, minimal VALU).
// EPILOGUE (changed vs R7): the 16 per-thread partials are reduced via an
// LDS transpose-reduce in the re-aliased 32 KB hash region, replacing
// 16 x 6-step __shfl chains (96 dependent ds_bpermute per wave, serialized
// at VGPR=32) with conflict-free ds_write/ds_read strips + ONE 5-step shfl.
__launch_bounds__(512, 8)
__global__ void fused_stats_mlp_xt(const float* __restrict__ XT,
                                   const int* __restrict__ y,
                                   const float* __restrict__ counts,
                                   const float* __restrict__ w1,
                                   const float* __restrict__ b1,
                                   const float* __restrict__ w2,
                                   const float* __restrict__ b2,
                                   float* __restrict__ out) {
    __shared__ __align__(16) unsigned int hash[HSIZE];   // 32 KB, multi-purpose

    const int w = blockIdx.x;
    const int g = (w & 7) * 1024 + (w >> 3);   // XCD swizzle, bijection over [0,8192)
    const int b = g >> 9;
    const int f = g & (NF - 1);
    const int tid = threadIdx.x;
    const int wave = tid >> 6;

    // vectorized hash init: 4x ds_write_b128 per thread
    uint4* h4 = (uint4*)hash;
    const uint4 e4 = make_uint4(HEMPTY, HEMPTY, HEMPTY, HEMPTY);
    #pragma unroll
    for (int i = 0; i < HSIZE / 4 / 512; i++) h4[i * 512 + tid] = e4;
    __syncthreads();

    const float4* Xc4 = (const float4*)(XT + ((size_t)b * NF + f) * NS);
    const int4*   yp4 = (const int4*)(y + (size_t)b * NS);

    float sum = 0.f, sumsq = 0.f, sumabs = 0.f, maxabs = 0.f, nancnt = 0.f, uniq = 0.f;
    float csum[NC];
    #pragma unroll
    for (int c = 0; c < NC; c++) csum[c] = 0.f;

    if (wave < 4) {
        // ---------------- stats role: 16 elements/thread, no DS ops --------------
        const int ts = tid;                        // 0..255
        float4 xv[4]; int4 yv[4];
        #pragma unroll
        for (int k = 0; k < 4; k++) {
            xv[k] = Xc4[k * 256 + ts];
            yv[k] = yp4[k * 256 + ts];
        }
        #pragma unroll
        for (int k = 0; k < 4; k++) {
            const float xe[4] = { xv[k].x, xv[k].y, xv[k].z, xv[k].w };
            const int   ye[4] = { yv[k].x, yv[k].y, yv[k].z, yv[k].w };
            #pragma unroll
            for (int j = 0; j < 4; j++) {
                float x = xe[j];
                if (x != x) { nancnt += 1.f; x = 0.f; }   // nan_to_num
                sum += x;
                sumsq = fmaf(x, x, sumsq);
                const float a = fabsf(x);
                sumabs += a;
                maxabs = fmaxf(maxabs, a);
                const int yc = ye[j];
                #pragma unroll
                for (int c = 0; c < NC; c++) csum[c] += (yc == c) ? x : 0.f;
            }
        }
    } else {
        // ---------------- hash role: 16 elements/thread, batched CAS -------------
        const int th = tid - 256;                  // 0..255
        const float4 xa = Xc4[th];
        const float4 xb = Xc4[256 + th];
        const float4 xc = Xc4[512 + th];
        const float4 xd = Xc4[768 + th];
        uniq += hash8(hash, xa, xb);
        uniq += hash8(hash, xc, xd);
    }

    __syncthreads();   // ALL hash CAS complete before re-aliasing the region

    // -------- epilogue: LDS transpose-reduce of the 16 partials ------------------
    // r2 laid out as [16 stats][512 threads] floats = exactly 32 KB.
    // write: word addr = c*512 + tid -> bank tid&31 (2 lanes/bank, free)
    // read:  thread t sums stat c=t>>5 over strip q=t&31, rows q+32j -> bank q (free)
    float* r2 = (float*)hash;
    {
        float v16[16] = { sum, sumsq, sumabs, nancnt, uniq, maxabs,
                          csum[0], csum[1], csum[2], csum[3], csum[4],
                          csum[5], csum[6], csum[7], csum[8], csum[9] };
        #pragma unroll
        for (int c = 0; c < 16; c++) r2[c * 512 + tid] = v16[c];
    }
    __syncthreads();

    const int rc = tid >> 5;          // stat index 0..15
    const int rq = tid & 31;          // strip index 0..31
    float part = 0.f;
    #pragma unroll
    for (int j = 0; j < 16; j++) {    // 16 independent, pipelined ds_read_b32
        const float v = r2[rc * 512 + rq + 32 * j];
        part = (rc == 5) ? fmaxf(part, v) : part + v;
    }
    // 32 partials of each stat live in 32 CONTIGUOUS lanes -> one 5-step reduce
    #pragma unroll
    for (int off = 16; off > 0; off >>= 1) {
        const float o = __shfl_down(part, off, 32);
        part = (rc == 5) ? fmaxf(part, o) : part + o;
    }
    __syncthreads();                  // all r2 reads done before overwrite
    if (rq == 0) r2[rc] = part;       // totals at words [0,16)
    __syncthreads();

    float* stats_s = r2 + 32;         // words [32,38)
    float* h_s     = r2 + 64;         // words [64,128)

    if (tid == 0) {
        float t[16];
        #pragma unroll
        for (int v = 0; v < 16; v++) t[v] = r2[v];
        const float invS = 1.f / (float)NS;
        const float gmean    = t[0] * invS;
        const float variance = fmaxf(t[1] * invS - gmean * gmean, 0.f);  // biased
        const float mean_abs = t[2] * invS;
        const float missing  = t[3] * invS;
        const float n_unique = t[4];
        const float max_abs  = t[5];
        float between = 0.f;
        #pragma unroll
        for (int c = 0; c < NC; c++) {
            const float cnt = counts[b * NC + c];
            const float cm  = t[6 + c] / fmaxf(cnt, 1.f);
            const float d   = cm - gmean;
            between = fmaf(cnt * d, d, between);
        }
        between *= invS;                                   // counts.sum() == NS
        const float target = between / fmaxf(variance, 1e-6f);
        float st[6] = { target, missing, n_unique * invS, variance, mean_abs, max_abs };
        #pragma unroll
        for (int i = 0; i < 6; i++) {
            float v = st[i];
            if (!(fabsf(v) < INFINITY)) v = 0.f;           // nan_to_num
            stats_s[i] = v;
        }
    }
    __syncthreads();

    // MLP epilogue: 6 -> 64 (exact GELU) -> 128
    if (tid < 64) {
        float z = b1[tid];
        #pragma unroll
        for (int i = 0; i < 6; i++) z = fmaf(stats_s[i], w1[i * 64 + tid], z);
        h_s[tid] = 0.5f * z * (1.f + erff(z * 0.70710678118654752440f));
    }
    __syncthreads();
    if (tid < 128) {
        float o = b2[tid];
        #pragma unroll
        for (int j = 0; j < 64; j++) o = fmaf(h_s[j], w2[j * 128 + tid], o);
        out[(size_t)g * 128 + tid] = o;
    }
}

// ---------------- kernel 2 (fallback): round-0 strided version ----------------
__launch_bounds__(256)
__global__ void fused_stats_mlp_kernel(const float* __restrict__ X,
                                       const int* __restrict__ y,
                                       const float* __restrict__ counts,
                                       const float* __restrict__ w1,
                                       const float* __restrict__ b1,
                                       const float* __restrict__ w2,
                                       const float* __restrict__ b2,
                                       float* __restrict__ out) {
    __shared__ unsigned int hash[HSIZE];
    __shared__ float red[4][16];
    __shared__ float stats_s[6];
    __shared__ float h_s[64];

    const int w = blockIdx.x;
    const int g = (w & 7) * 1024 + (w >> 3);
    const int b = g >> 9;
    const int f = g & (NF - 1);
    const int tid = threadIdx.x;

    #pragma unroll
    for (int i = 0; i < HSIZE / 256; i++) hash[tid + i * 256] = HEMPTY;
    __syncthreads();

    const float* Xp = X + (size_t)b * NS * NF + f;
    const int*   yp = y + b * NS;

    float sum = 0.f, sumsq = 0.f, sumabs = 0.f, maxabs = 0.f, nancnt = 0.f, uniq = 0.f;
    float csum[NC];
    #pragma unroll
    for (int c = 0; c < NC; c++) csum[c] = 0.f;

    #pragma unroll
    for (int k0 = 0; k0 < 16; k0 += 8) {
        float xv[8]; int yv[8];
        #pragma unroll
        for (int k = 0; k < 8; k++) {
            const int s = (k0 + k) * 256 + tid;
            xv[k] = Xp[(size_t)s * NF];
            yv[k] = yp[s];
        }
        #pragma unroll
        for (int k = 0; k < 8; k++) {
            float x = xv[k];
            if (x != x) { nancnt += 1.f; x = 0.f; }
            sum += x;
            sumsq = fmaf(x, x, sumsq);
            const float a = fabsf(x);
            sumabs += a;
            maxabs = fmaxf(maxabs, a);
            const int yc = yv[k];
            #pragma unroll
            for (int c = 0; c < NC; c++) csum[c] += (yc == c) ? x : 0.f;
            unsigned int pat = __float_as_uint(x);
            if (pat == 0x80000000u) pat = 0u;
            unsigned int slot = (pat * 2654435761u) >> 19;
            for (;;) {
                const unsigned int old = atomicCAS(&hash[slot], HEMPTY, pat);
                if (old == HEMPTY) { uniq += 1.f; break; }
                if (old == pat) break;
                slot = (slot + 1) & HMASK;
            }
        }
    }

    sum    = wave_reduce_add(sum);
    sumsq  = wave_reduce_add(sumsq);
    sumabs = wave_reduce_add(sumabs);
    nancnt = wave_reduce_add(nancnt);
    uniq   = wave_reduce_add(uniq);
    maxabs = wave_reduce_max(maxabs);
    #pragma unroll
    for (int c = 0; c < NC; c++) csum[c] = wave_reduce_add(csum[c]);

    const int wave = tid >> 6, lane = tid & 63;
    if (lane == 0) {
        red[wave][0] = sum;    red[wave][1] = sumsq; red[wave][2] = sumabs;
        red[wave][3] = nancnt; red[wave][4] = uniq;  red[wave][5] = maxabs;
        #pragma unroll
        for (int c = 0; c < NC; c++) red[wave][6 + c] = csum[c];
    }
    __syncthreads();

    if (tid == 0) {
        float t[16];
        #pragma unroll
        for (int v = 0; v < 16; v++) t[v] = red[0][v];
        #pragma unroll
        for (int wv = 1; wv < 4; wv++) {
            #pragma unroll
            for (int v = 0; v < 16; v++) {
                if (v == 5) t[v] = fmaxf(t[v], red[wv][v]);
                else        t[v] += red[wv][v];
            }
        }
        const float invS = 1.f / (float)NS;
        const float gmean    = t[0] * invS;
        const float variance = fmaxf(t[1] * invS - gmean * gmean, 0.f);
        const float mean_abs = t[2] * invS;
        const float missing  = t[3] * invS;
        const float n_unique = t[4];
        const float max_abs  = t[5];
        float between = 0.f;
        #pragma unroll
        for (int c = 0; c < NC; c++) {
            const float cnt = counts[b * NC + c];
            const float cm  = t[6 + c] / fmaxf(cnt, 1.f);
            const float d   = cm - gmean;
            between += cnt * d * d;
        }
        between *= invS;
        const float target = between / fmaxf(variance, 1e-6f);
        float st[6] = { target, missing, n_unique * invS, variance, mean_abs, max_abs };
        #pragma unroll
        for (int i = 0; i < 6; i++) {
            float v = st[i];
            if (!(fabsf(v) < INFINITY)) v = 0.f;
            stats_s[i] = v;
        }
    }
    __syncthreads();

    if (tid < 64) {
        float z = b1[tid];
        #pragma unroll
        for (int i = 0; i < 6; i++) z = fmaf(stats_s[i], w1[i * 64 + tid], z);
        h_s[tid] = 0.5f * z * (1.f + erff(z * 0.70710678118654752440f));
    }
    __syncthreads();
    if (tid < 128) {
        float o = b2[tid];
        #pragma unroll
        for (int j = 0; j < 64; j++) o = fmaf(h_s[j], w2[j * 128 + tid], o);
        out[(size_t)g * 128 + tid] = o;
    }
}

extern "C" void kernel_launch(void* const* d_in, const int* in_sizes, int n_in,
                              void* d_out, int out_size, void* d_ws, size_t ws_size,
                              hipStream_t stream) {
    const float* X  = (const float*)d_in[0];
    const int*   y  = (const int*)d_in[1];
    const float* w1 = (const float*)d_in[2];
    const float* b1 = (const float*)d_in[3];
    const float* w2 = (const float*)d_in[4];
    const float* b2 = (const float*)d_in[5];
    float* out    = (float*)d_out;
    float* counts = (float*)d_ws;          // 16*10 floats at workspace base

    const size_t xt_bytes = (size_t)NB * NF * NS * sizeof(float);   // 128 MB
    if (ws_size >= xt_bytes + WS_XT_OFF) {
        float* XT = (float*)((char*)d_ws + WS_XT_OFF);
        transpose_kernel<<<dim3(NB, NS / 64, NF / 64), 256, 0, stream>>>(X, XT, y, counts);
        fused_stats_mlp_xt<<<NB * NF, 512, 0, stream>>>(XT, y, counts, w1, b1, w2, b2, out);
    } else {
        // workspace too small: proven strided path (round-0 structure)
        count_classes_kernel<<<NB, 256, 0, stream>>>(y, counts);
        fused_stats_mlp_kernel<<<NB * NF, 256, 0, stream>>>(X, y, counts, w1, b1, w2, b2, out);
    }
}

// Round 9
// 325.814 us; speedup vs baseline: 1.1931x; 1.0698x over previous
//
#include <hip/hip_runtime.h>
#include <math.h>

#define NS 4096
#define NF 512
#define NB 16
#define NC 10
#define HSIZE 8192
#define HMASK 8191
#define HEMPTY 0xFFFFFFFFu
#define TSR 128                      // stripe tile rows
#define TSC 16                       // stripe cols
#define WS_P_OFF  1024
#define WS_XT_OFF (1024 + NB * NF * 16 * 4)   // counts | P[B][F][16] | XT

// ---------------- helpers ----------------
__device__ __forceinline__ float wave_reduce_add(float v) {
    #pragma unroll
    for (int off = 32; off > 0; off >>= 1) v += __shfl_down(v, off, 64);
    return v;
}
__device__ __forceinline__ float wave_reduce_max(float v) {
    #pragma unroll
    for (int off = 32; off > 0; off >>= 1) v = fmaxf(v, __shfl_down(v, off, 64));
    return v;
}

__device__ __forceinline__ unsigned int pat_of(float x) {
    if (x != x) x = 0.f;                       // nan_to_num for the hash
    unsigned int p = __float_as_uint(x);
    return (p == 0x80000000u) ? 0u : p;        // -0.0 == +0.0 value semantics
}

__device__ __forceinline__ float resolve1(unsigned int* hash,
                                          unsigned int s, unsigned int p, unsigned int o) {
    if (o == HEMPTY) return 1.f;               // first insertion of this value
    if (o == p)      return 0.f;               // duplicate
    for (;;) {
        s = (s + 1) & HMASK;
        const unsigned int oo = atomicCAS(&hash[s], HEMPTY, p);
        if (oo == HEMPTY) return 1.f;
        if (oo == p)      return 0.f;
    }
}

// 8 elements: issue 8 independent CAS back-to-back, then resolve.
__device__ __forceinline__ float hash8(unsigned int* hash, const float4 u, const float4 v) {
    const unsigned int p0 = pat_of(u.x), p1 = pat_of(u.y), p2 = pat_of(u.z), p3 = pat_of(u.w);
    const unsigned int p4 = pat_of(v.x), p5 = pat_of(v.y), p6 = pat_of(v.z), p7 = pat_of(v.w);
    const unsigned int s0 = (p0 * 2654435761u) >> 19, s1 = (p1 * 2654435761u) >> 19;
    const unsigned int s2 = (p2 * 2654435761u) >> 19, s3 = (p3 * 2654435761u) >> 19;
    const unsigned int s4 = (p4 * 2654435761u) >> 19, s5 = (p5 * 2654435761u) >> 19;
    const unsigned int s6 = (p6 * 2654435761u) >> 19, s7 = (p7 * 2654435761u) >> 19;
    const unsigned int o0 = atomicCAS(&hash[s0], HEMPTY, p0);
    const unsigned int o1 = atomicCAS(&hash[s1], HEMPTY, p1);
    const unsigned int o2 = atomicCAS(&hash[s2], HEMPTY, p2);
    const unsigned int o3 = atomicCAS(&hash[s3], HEMPTY, p3);
    const unsigned int o4 = atomicCAS(&hash[s4], HEMPTY, p4);
    const unsigned int o5 = atomicCAS(&hash[s5], HEMPTY, p5);
    const unsigned int o6 = atomicCAS(&hash[s6], HEMPTY, p6);
    const unsigned int o7 = atomicCAS(&hash[s7], HEMPTY, p7);
    float u8 = 0.f;
    u8 += resolve1(hash, s0, p0, o0);
    u8 += resolve1(hash, s1, p1, o1);
    u8 += resolve1(hash, s2, p2, o2);
    u8 += resolve1(hash, s3, p3, o3);
    u8 += resolve1(hash, s4, p4, o4);
    u8 += resolve1(hash, s5, p5, o5);
    u8 += resolve1(hash, s6, p6, o6);
    u8 += resolve1(hash, s7, p7, o7);
    return u8;
}

// ---------------- kernel S: stripe transpose + ALL moment stats + class counts ----
// one 512-thread block per (b, 16-col stripe). 32 iterations of 128x16 tiles:
// coalesced float4 row loads -> LDS[128][17] -> per-thread COLUMN stats
// (rows rq+32j: banks (17rq+col)&31, 17 coprime 32 -> 2-way, free) + float4
// XT column writes. Stats finish EXACTLY per (b,f) in-block (width-32 shfl) ->
// one P[b][f][16] store. No atomics, deterministic. The stats VALU (csum chain)
// hides under the stripe's memory latency (m114 co-scheduling).
__launch_bounds__(512, 4)
__global__ void stripe_stats_kernel(const float* __restrict__ X,
                                    float* __restrict__ XT,
                                    const int* __restrict__ y,
                                    float* __restrict__ P,
                                    float* __restrict__ counts) {
    __shared__ float t[TSR][TSC + 1];
    __shared__ int ys[TSR];
    __shared__ int hist[NC];
    const int b   = blockIdx.x;
    const int f0  = blockIdx.y * TSC;
    const int tid = threadIdx.x;
    const bool do_hist = (blockIdx.y == 0);
    if (do_hist && tid < NC) hist[tid] = 0;   // ordered before use by iter-0 syncs

    const int lrow = tid >> 2, lq = tid & 3;   // load mapping: 128 rows x 4 quads
    const int col  = tid >> 5, rq = tid & 31;  // stats mapping: 16 cols x 32 lanes

    const float* Xb = X + (size_t)b * NS * NF + f0 + lq * 4;
    const int*   yb = y + (size_t)b * NS;

    float sum = 0.f, sumsq = 0.f, sumabs = 0.f, maxabs = 0.f, nancnt = 0.f;
    float csum[NC];
    #pragma unroll
    for (int c = 0; c < NC; c++) csum[c] = 0.f;

    // software pipeline: load tile k+1 while processing tile k
    float4 xcur = *(const float4*)(Xb + (size_t)lrow * NF);
    int4 ycur = make_int4(0, 0, 0, 0);
    if (tid < TSR / 4) ycur = *(const int4*)(yb + tid * 4);

    for (int it = 0; it < NS / TSR; ++it) {
        const int s0 = it * TSR;
        float4 xnext = xcur; int4 ynext = ycur;
        if (it + 1 < NS / TSR) {
            xnext = *(const float4*)(Xb + (size_t)(s0 + TSR + lrow) * NF);
            if (tid < TSR / 4) ynext = *(const int4*)(yb + s0 + TSR + tid * 4);
        }
        __syncthreads();                       // prior tile's LDS reads complete
        t[lrow][lq * 4 + 0] = xcur.x; t[lrow][lq * 4 + 1] = xcur.y;
        t[lrow][lq * 4 + 2] = xcur.z; t[lrow][lq * 4 + 3] = xcur.w;
        if (tid < TSR / 4) {
            ys[tid * 4 + 0] = ycur.x; ys[tid * 4 + 1] = ycur.y;
            ys[tid * 4 + 2] = ycur.z; ys[tid * 4 + 3] = ycur.w;
        }
        __syncthreads();                       // tile ready
        if (do_hist && tid < TSR) atomicAdd(&hist[ys[tid]], 1);

        #pragma unroll
        for (int j = 0; j < 4; j++) {          // rows rq+32j: conflict-free reads
            const int r = rq + 32 * j;
            float x = t[r][col];
            const int yc = ys[r];
            if (x != x) { nancnt += 1.f; x = 0.f; }          // nan_to_num
            sum += x;
            sumsq = fmaf(x, x, sumsq);
            const float a = fabsf(x);
            sumabs += a;
            maxabs = fmaxf(maxabs, a);
            #pragma unroll
            for (int c = 0; c < NC; c++) csum[c] += (yc == c) ? x : 0.f;
        }
        // XT write: RAW values (hash does its own nan/-0 normalization)
        float4 wv;
        wv.x = t[rq * 4 + 0][col]; wv.y = t[rq * 4 + 1][col];
        wv.z = t[rq * 4 + 2][col]; wv.w = t[rq * 4 + 3][col];
        *(float4*)(XT + ((size_t)b * NF + f0 + col) * NS + s0 + rq * 4) = wv;

        xcur = xnext; ycur = ynext;
    }

    // exact per-column totals: width-32 shfl reduce, lane rq==0 stores 15 stats
    float st[16] = { sum, sumsq, sumabs, nancnt, maxabs,
                     csum[0], csum[1], csum[2], csum[3], csum[4],
                     csum[5], csum[6], csum[7], csum[8], csum[9], 0.f };
    #pragma unroll
    for (int s = 0; s < 15; s++) {
        float v = st[s];
        #pragma unroll
        for (int off = 16; off > 0; off >>= 1) {
            const float o = __shfl_down(v, off, 32);
            v = (s == 4) ? fmaxf(v, o) : v + o;
        }
        if (rq == 0) P[((size_t)b * NF + f0 + col) * 16 + s] = v;
    }
    if (do_hist) {
        __syncthreads();                       // all hist atomics done
        if (tid < NC) counts[b * NC + tid] = (float)hist[tid];
    }
}

// ---------------- kernel 2 (fast): hash-unique + finalize + MLP on XT -------------
// 512 threads per (b,f) column; ALL 8 waves hash (8 elem/thread, batched CAS).
// Moment stats arrive precomputed in P — fused VALU load collapses.
__launch_bounds__(512, 8)
__global__ void fused_hash_mlp(const float* __restrict__ XT,
                               const float* __restrict__ P,
                               const float* __restrict__ counts,
                               const float* __restrict__ w1,
                               const float* __restrict__ b1,
                               const float* __restrict__ w2,
                               const float* __restrict__ b2,
                               float* __restrict__ out) {
    __shared__ __align__(16) unsigned int hash[HSIZE];   // 32 KB, multi-purpose

    const int w = blockIdx.x;
    const int g = (w & 7) * 1024 + (w >> 3);   // XCD swizzle, bijection over [0,8192)
    const int b = g >> 9;
    const int f = g & (NF - 1);
    const int tid = threadIdx.x;
    const int wave = tid >> 6, lane = tid & 63;

    uint4* h4 = (uint4*)hash;
    const uint4 e4 = make_uint4(HEMPTY, HEMPTY, HEMPTY, HEMPTY);
    #pragma unroll
    for (int i = 0; i < HSIZE / 4 / 512; i++) h4[i * 512 + tid] = e4;
    __syncthreads();

    const float4* Xc4 = (const float4*)(XT + ((size_t)b * NF + f) * NS);
    const float4 xa = Xc4[tid];
    const float4 xb = Xc4[512 + tid];
    float uniq = hash8(hash, xa, xb);          // 512 x 8 = 4096 elements

    __syncthreads();                           // ALL CAS complete before re-alias

    float* r = (float*)hash;                   // [0,8): wave uniq partials
    float* stats_s = r + 32;                   // [32,38)
    float* h_s = r + 64;                       // [64,128)

    uniq = wave_reduce_add(uniq);
    if (lane == 0) r[wave] = uniq;
    __syncthreads();

    if (tid == 0) {
        float u = 0.f;
        #pragma unroll
        for (int i = 0; i < 8; i++) u += r[i];
        const float* Pp = P + ((size_t)b * NF + f) * 16;
        float S[15];
        #pragma unroll
        for (int s = 0; s < 15; s++) S[s] = Pp[s];
        const float invS = 1.f / (float)NS;
        const float gmean    = S[0] * invS;
        const float variance = fmaxf(S[1] * invS - gmean * gmean, 0.f);  // biased
        const float mean_abs = S[2] * invS;
        const float missing  = S[3] * invS;
        const float max_abs  = S[4];
        float between = 0.f;
        #pragma unroll
        for (int c = 0; c < NC; c++) {
            const float cnt = counts[b * NC + c];
            const float cm  = S[5 + c] / fmaxf(cnt, 1.f);
            const float d   = cm - gmean;
            between = fmaf(cnt * d, d, between);
        }
        between *= invS;                                   // counts.sum() == NS
        const float target = between / fmaxf(variance, 1e-6f);
        float st6[6] = { target, missing, u * invS, variance, mean_abs, max_abs };
        #pragma unroll
        for (int i = 0; i < 6; i++) {
            float v = st6[i];
            if (!(fabsf(v) < INFINITY)) v = 0.f;           // nan_to_num
            stats_s[i] = v;
        }
    }
    __syncthreads();

    // MLP epilogue: 6 -> 64 (exact GELU) -> 128
    if (tid < 64) {
        float z = b1[tid];
        #pragma unroll
        for (int i = 0; i < 6; i++) z = fmaf(stats_s[i], w1[i * 64 + tid], z);
        h_s[tid] = 0.5f * z * (1.f + erff(z * 0.70710678118654752440f));
    }
    __syncthreads();
    if (tid < 128) {
        float o = b2[tid];
        #pragma unroll
        for (int j = 0; j < 64; j++) o = fmaf(h_s[j], w2[j * 128 + tid], o);
        out[(size_t)g * 128 + tid] = o;
    }
}

// ---------------- fallback path (round-0 proven, strided) ----------------
__global__ void count_classes_kernel(const int* __restrict__ y, float* __restrict__ counts) {
    __shared__ int hist[NC];
    const int b = blockIdx.x;
    if (threadIdx.x < NC) hist[threadIdx.x] = 0;
    __syncthreads();
    for (int s = threadIdx.x; s < NS; s += blockDim.x)
        atomicAdd(&hist[y[b * NS + s]], 1);
    __syncthreads();
    if (threadIdx.x < NC) counts[b * NC + threadIdx.x] = (float)hist[threadIdx.x];
}

__launch_bounds__(256)
__global__ void fused_stats_mlp_kernel(const float* __restrict__ X,
                                       const int* __restrict__ y,
                                       const float* __restrict__ counts,
                                       const float* __restrict__ w1,
                                       const float* __restrict__ b1,
                                       const float* __restrict__ w2,
                                       const float* __restrict__ b2,
                                       float* __restrict__ out) {
    __shared__ unsigned int hash[HSIZE];
    __shared__ float red[4][16];
    __shared__ float stats_s[6];
    __shared__ float h_s[64];

    const int w = blockIdx.x;
    const int g = (w & 7) * 1024 + (w >> 3);
    const int b = g >> 9;
    const int f = g & (NF - 1);
    const int tid = threadIdx.x;

    #pragma unroll
    for (int i = 0; i < HSIZE / 256; i++) hash[tid + i * 256] = HEMPTY;
    __syncthreads();

    const float* Xp = X + (size_t)b * NS * NF + f;
    const int*   yp = y + b * NS;

    float sum = 0.f, sumsq = 0.f, sumabs = 0.f, maxabs = 0.f, nancnt = 0.f, uniq = 0.f;
    float csum[NC];
    #pragma unroll
    for (int c = 0; c < NC; c++) csum[c] = 0.f;

    #pragma unroll
    for (int k0 = 0; k0 < 16; k0 += 8) {
        float xv[8]; int yv[8];
        #pragma unroll
        for (int k = 0; k < 8; k++) {
            const int s = (k0 + k) * 256 + tid;
            xv[k] = Xp[(size_t)s * NF];
            yv[k] = yp[s];
        }
        #pragma unroll
        for (int k = 0; k < 8; k++) {
            float x = xv[k];
            if (x != x) { nancnt += 1.f; x = 0.f; }
            sum += x;
            sumsq = fmaf(x, x, sumsq);
            const float a = fabsf(x);
            sumabs += a;
            maxabs = fmaxf(maxabs, a);
            const int yc = yv[k];
            #pragma unroll
            for (int c = 0; c < NC; c++) csum[c] += (yc == c) ? x : 0.f;
            unsigned int pat = __float_as_uint(x);
            if (pat == 0x80000000u) pat = 0u;
            unsigned int slot = (pat * 2654435761u) >> 19;
            for (;;) {
                const unsigned int old = atomicCAS(&hash[slot], HEMPTY, pat);
                if (old == HEMPTY) { uniq += 1.f; break; }
                if (old == pat) break;
                slot = (slot + 1) & HMASK;
            }
        }
    }

    sum    = wave_reduce_add(sum);
    sumsq  = wave_reduce_add(sumsq);
    sumabs = wave_reduce_add(sumabs);
    nancnt = wave_reduce_add(nancnt);
    uniq   = wave_reduce_add(uniq);
    maxabs = wave_reduce_max(maxabs);
    #pragma unroll
    for (int c = 0; c < NC; c++) csum[c] = wave_reduce_add(csum[c]);

    const int wave = tid >> 6, lane = tid & 63;
    if (lane == 0) {
        red[wave][0] = sum;    red[wave][1] = sumsq; red[wave][2] = sumabs;
        red[wave][3] = nancnt; red[wave][4] = uniq;  red[wave][5] = maxabs;
        #pragma unroll
        for (int c = 0; c < NC; c++) red[wave][6 + c] = csum[c];
    }
    __syncthreads();

    if (tid == 0) {
        float t[16];
        #pragma unroll
        for (int v = 0; v < 16; v++) t[v] = red[0][v];
        #pragma unroll
        for (int wv = 1; wv < 4; wv++) {
            #pragma unroll
            for (int v = 0; v < 16; v++) {
                if (v == 5) t[v] = fmaxf(t[v], red[wv][v]);
                else        t[v] += red[wv][v];
            }
        }
        const float invS = 1.f / (float)NS;
        const float gmean    = t[0] * invS;
        const float variance = fmaxf(t[1] * invS - gmean * gmean, 0.f);
        const float mean_abs = t[2] * invS;
        const float missing  = t[3] * invS;
        const float n_unique = t[4];
        const float max_abs  = t[5];
        float between = 0.f;
        #pragma unroll
        for (int c = 0; c < NC; c++) {
            const float cnt = counts[b * NC + c];
            const float cm  = t[6 + c] / fmaxf(cnt, 1.f);
            const float d   = cm - gmean;
            between += cnt * d * d;
        }
        between *= invS;
        const float target = between / fmaxf(variance, 1e-6f);
        float st[6] = { target, missing, n_unique * invS, variance, mean_abs, max_abs };
        #pragma unroll
        for (int i = 0; i < 6; i++) {
            float v = st[i];
            if (!(fabsf(v) < INFINITY)) v = 0.f;
            stats_s[i] = v;
        }
    }
    __syncthreads();

    if (tid < 64) {
        float z = b1[tid];
        #pragma unroll
        for (int i = 0; i < 6; i++) z = fmaf(stats_s[i], w1[i * 64 + tid], z);
        h_s[tid] = 0.5f * z * (1.f + erff(z * 0.70710678118654752440f));
    }
    __syncthreads();
    if (tid < 128) {
        float o = b2[tid];
        #pragma unroll
        for (int j = 0; j < 64; j++) o = fmaf(h_s[j], w2[j * 128 + tid], o);
        out[(size_t)g * 128 + tid] = o;
    }
}

extern "C" void kernel_launch(void* const* d_in, const int* in_sizes, int n_in,
                              void* d_out, int out_size, void* d_ws, size_t ws_size,
                              hipStream_t stream) {
    const float* X  = (const float*)d_in[0];
    const int*   y  = (const int*)d_in[1];
    const float* w1 = (const float*)d_in[2];
    const float* b1 = (const float*)d_in[3];
    const float* w2 = (const float*)d_in[4];
    const float* b2 = (const float*)d_in[5];
    float* out    = (float*)d_out;
    float* counts = (float*)d_ws;          // 16*10 floats at workspace base

    const size_t xt_bytes = (size_t)NB * NF * NS * sizeof(float);   // 128 MB
    if (ws_size >= (size_t)WS_XT_OFF + xt_bytes) {
        float* P  = (float*)((char*)d_ws + WS_P_OFF);
        float* XT = (float*)((char*)d_ws + WS_XT_OFF);
        stripe_stats_kernel<<<dim3(NB, NF / TSC), 512, 0, stream>>>(X, XT, y, P, counts);
        fused_hash_mlp<<<NB * NF, 512, 0, stream>>>(XT, P, counts, w1, b1, w2, b2, out);
    } else {
        // workspace too small: proven strided path (round-0 structure)
        count_classes_kernel<<<NB, 256, 0, stream>>>(y, counts);
        fused_stats_mlp_kernel<<<NB * NF, 256, 0, stream>>>(X, y, counts, w1, b1, w2, b2, out);
    }
}

// Round 10
// 323.471 us; speedup vs baseline: 1.2018x; 1.0072x over previous
//
#include <hip/hip_runtime.h>
#include <math.h>

#define NS 4096
#define NF 512
#define NB 16
#define NC 10
#define HSIZE 8192
#define HMASK 8191
#define HEMPTY 0xFFFFFFFFu
#define TSR 128                      // stripe tile rows
#define TSC 16                       // stripe cols
#define NSEG 4                       // segments along S
#define SEGR (NS / NSEG)             // 1024 rows per segment
#define WS_P_OFF  1024
#define P2_BYTES (NB * NF * NSEG * 16 * 4)            // 2 MB
#define WS_XT_OFF (WS_P_OFF + P2_BYTES)               // counts | P2 | XT

// ---------------- helpers ----------------
__device__ __forceinline__ float wave_reduce_add(float v) {
    #pragma unroll
    for (int off = 32; off > 0; off >>= 1) v += __shfl_down(v, off, 64);
    return v;
}

__device__ __forceinline__ unsigned int pat_of(float x) {
    if (x != x) x = 0.f;                       // nan_to_num for the hash
    unsigned int p = __float_as_uint(x);
    return (p == 0x80000000u) ? 0u : p;        // -0.0 == +0.0 value semantics
}

__device__ __forceinline__ float resolve1(unsigned int* hash,
                                          unsigned int s, unsigned int p, unsigned int o) {
    if (o == HEMPTY) return 1.f;               // first insertion of this value
    if (o == p)      return 0.f;               // duplicate
    for (;;) {
        s = (s + 1) & HMASK;
        const unsigned int oo = atomicCAS(&hash[s], HEMPTY, p);
        if (oo == HEMPTY) return 1.f;
        if (oo == p)      return 0.f;
    }
}

// 8 elements: issue 8 independent CAS back-to-back, then resolve.
__device__ __forceinline__ float hash8(unsigned int* hash, const float4 u, const float4 v) {
    const unsigned int p0 = pat_of(u.x), p1 = pat_of(u.y), p2 = pat_of(u.z), p3 = pat_of(u.w);
    const unsigned int p4 = pat_of(v.x), p5 = pat_of(v.y), p6 = pat_of(v.z), p7 = pat_of(v.w);
    const unsigned int s0 = (p0 * 2654435761u) >> 19, s1 = (p1 * 2654435761u) >> 19;
    const unsigned int s2 = (p2 * 2654435761u) >> 19, s3 = (p3 * 2654435761u) >> 19;
    const unsigned int s4 = (p4 * 2654435761u) >> 19, s5 = (p5 * 2654435761u) >> 19;
    const unsigned int s6 = (p6 * 2654435761u) >> 19, s7 = (p7 * 2654435761u) >> 19;
    const unsigned int o0 = atomicCAS(&hash[s0], HEMPTY, p0);
    const unsigned int o1 = atomicCAS(&hash[s1], HEMPTY, p1);
    const unsigned int o2 = atomicCAS(&hash[s2], HEMPTY, p2);
    const unsigned int o3 = atomicCAS(&hash[s3], HEMPTY, p3);
    const unsigned int o4 = atomicCAS(&hash[s4], HEMPTY, p4);
    const unsigned int o5 = atomicCAS(&hash[s5], HEMPTY, p5);
    const unsigned int o6 = atomicCAS(&hash[s6], HEMPTY, p6);
    const unsigned int o7 = atomicCAS(&hash[s7], HEMPTY, p7);
    float u8 = 0.f;
    u8 += resolve1(hash, s0, p0, o0);
    u8 += resolve1(hash, s1, p1, o1);
    u8 += resolve1(hash, s2, p2, o2);
    u8 += resolve1(hash, s3, p3, o3);
    u8 += resolve1(hash, s4, p4, o4);
    u8 += resolve1(hash, s5, p5, o5);
    u8 += resolve1(hash, s6, p6, o6);
    u8 += resolve1(hash, s7, p7, o7);
    return u8;
}

// ---------------- kernel S: segmented stripe transpose + moment stats --------------
// one 512-thread block per (b, 16-col stripe, 1024-row segment) -> 2048 blocks
// (R9's 512 blocks left the machine half idle). Per 128x16 tile: coalesced
// float4 row loads -> LDS[128][17] -> per-thread column stats + float4 XT
// column writes. Per-segment partials stored non-atomically to P2 (exact,
// deterministic); y histogram via LDS + one integer global atomicAdd per (b,c).
__launch_bounds__(512, 4)
__global__ void stripe_stats_kernel(const float* __restrict__ X,
                                    float* __restrict__ XT,
                                    const int* __restrict__ y,
                                    float* __restrict__ P2,
                                    int* __restrict__ counts_i) {
    __shared__ float t[TSR][TSC + 1];
    __shared__ int ys[TSR];
    __shared__ int hist[NC];
    const int b   = blockIdx.x;
    const int f0  = blockIdx.y * TSC;
    const int seg = blockIdx.z;
    const int tid = threadIdx.x;
    const bool do_hist = (blockIdx.y == 0);
    if (do_hist && tid < NC) hist[tid] = 0;    // ordered before use by iter-0 syncs

    const int lrow = tid >> 2, lq = tid & 3;   // load mapping: 128 rows x 4 quads
    const int col  = tid >> 5, rq = tid & 31;  // stats mapping: 16 cols x 32 lanes

    const int sbase = seg * SEGR;
    const float* Xb = X + (size_t)b * NS * NF + f0 + lq * 4;
    const int*   yb = y + (size_t)b * NS;

    float sum = 0.f, sumsq = 0.f, sumabs = 0.f, maxabs = 0.f, nancnt = 0.f;
    float csum[NC];
    #pragma unroll
    for (int c = 0; c < NC; c++) csum[c] = 0.f;

    // software pipeline: load tile k+1 while processing tile k
    float4 xcur = *(const float4*)(Xb + (size_t)(sbase + lrow) * NF);
    int4 ycur = make_int4(0, 0, 0, 0);
    if (tid < TSR / 4) ycur = *(const int4*)(yb + sbase + tid * 4);

    for (int it = 0; it < SEGR / TSR; ++it) {  // 8 tiles per segment
        const int s0 = sbase + it * TSR;
        float4 xnext = xcur; int4 ynext = ycur;
        if (it + 1 < SEGR / TSR) {
            xnext = *(const float4*)(Xb + (size_t)(s0 + TSR + lrow) * NF);
            if (tid < TSR / 4) ynext = *(const int4*)(yb + s0 + TSR + tid * 4);
        }
        __syncthreads();                       // prior tile's LDS reads complete
        t[lrow][lq * 4 + 0] = xcur.x; t[lrow][lq * 4 + 1] = xcur.y;
        t[lrow][lq * 4 + 2] = xcur.z; t[lrow][lq * 4 + 3] = xcur.w;
        if (tid < TSR / 4) {
            ys[tid * 4 + 0] = ycur.x; ys[tid * 4 + 1] = ycur.y;
            ys[tid * 4 + 2] = ycur.z; ys[tid * 4 + 3] = ycur.w;
        }
        __syncthreads();                       // tile ready
        if (do_hist && tid < TSR) atomicAdd(&hist[ys[tid]], 1);

        #pragma unroll
        for (int j = 0; j < 4; j++) {          // rows rq+32j: conflict-free reads
            const int r = rq + 32 * j;
            float x = t[r][col];
            const int yc = ys[r];
            if (x != x) { nancnt += 1.f; x = 0.f; }          // nan_to_num
            sum += x;
            sumsq = fmaf(x, x, sumsq);
            const float a = fabsf(x);
            sumabs += a;
            maxabs = fmaxf(maxabs, a);
            #pragma unroll
            for (int c = 0; c < NC; c++) csum[c] += (yc == c) ? x : 0.f;
        }
        // XT write: RAW values (hash does its own nan/-0 normalization)
        float4 wv;
        wv.x = t[rq * 4 + 0][col]; wv.y = t[rq * 4 + 1][col];
        wv.z = t[rq * 4 + 2][col]; wv.w = t[rq * 4 + 3][col];
        *(float4*)(XT + ((size_t)b * NF + f0 + col) * NS + s0 + rq * 4) = wv;

        xcur = xnext; ycur = ynext;
    }

    // per-segment partials: width-32 shfl reduce, lane rq==0 stores 15 stats
    float st[15] = { sum, sumsq, sumabs, nancnt, maxabs,
                     csum[0], csum[1], csum[2], csum[3], csum[4],
                     csum[5], csum[6], csum[7], csum[8], csum[9] };
    #pragma unroll
    for (int s = 0; s < 15; s++) {
        float v = st[s];
        #pragma unroll
        for (int off = 16; off > 0; off >>= 1) {
            const float o = __shfl_down(v, off, 32);
            v = (s == 4) ? fmaxf(v, o) : v + o;
        }
        if (rq == 0)
            P2[(((size_t)b * NF + f0 + col) * NSEG + seg) * 16 + s] = v;
    }
    if (do_hist) {
        __syncthreads();                       // all hist atomics done
        if (tid < NC) atomicAdd(&counts_i[b * NC + tid], hist[tid]);
    }
}

// ---------------- kernel 2 (fast): hash-unique + finalize + MLP on XT -------------
// 512 threads per (b,f) column; ALL 8 waves hash (8 elem/thread, batched CAS).
// XT loads issued BEFORE table init -> HBM latency hides under init+barrier.
__launch_bounds__(512, 8)
__global__ void fused_hash_mlp(const float* __restrict__ XT,
                               const float* __restrict__ P2,
                               const int* __restrict__ counts_i,
                               const float* __restrict__ w1,
                               const float* __restrict__ b1,
                               const float* __restrict__ w2,
                               const float* __restrict__ b2,
                               float* __restrict__ out) {
    __shared__ __align__(16) unsigned int hash[HSIZE];   // 32 KB, multi-purpose

    const int w = blockIdx.x;
    const int g = (w & 7) * 1024 + (w >> 3);   // XCD swizzle, bijection over [0,8192)
    const int b = g >> 9;
    const int f = g & (NF - 1);
    const int tid = threadIdx.x;
    const int wave = tid >> 6, lane = tid & 63;

    // prefetch BEFORE init: loads in flight while the table is cleared
    const float4* Xc4 = (const float4*)(XT + ((size_t)b * NF + f) * NS);
    const float4 xa = Xc4[tid];
    const float4 xb = Xc4[512 + tid];

    uint4* h4 = (uint4*)hash;
    const uint4 e4 = make_uint4(HEMPTY, HEMPTY, HEMPTY, HEMPTY);
    #pragma unroll
    for (int i = 0; i < HSIZE / 4 / 512; i++) h4[i * 512 + tid] = e4;
    __syncthreads();

    float uniq = hash8(hash, xa, xb);          // 512 x 8 = 4096 elements

    __syncthreads();                           // ALL CAS complete before re-alias

    float* r = (float*)hash;                   // [0,8): wave uniq partials
    float* stats_s = r + 32;                   // [32,38)
    float* h_s = r + 64;                       // [64,128)

    uniq = wave_reduce_add(uniq);
    if (lane == 0) r[wave] = uniq;
    __syncthreads();

    if (tid == 0) {
        float u = 0.f;
        #pragma unroll
        for (int i = 0; i < 8; i++) u += r[i];
        const float* Pp = P2 + ((size_t)b * NF + f) * (NSEG * 16);
        float S[15];
        #pragma unroll
        for (int s = 0; s < 15; s++) {
            float v0 = Pp[s], v1 = Pp[16 + s], v2 = Pp[32 + s], v3 = Pp[48 + s];
            S[s] = (s == 4) ? fmaxf(fmaxf(v0, v1), fmaxf(v2, v3))
                            : (v0 + v1) + (v2 + v3);
        }
        const float invS = 1.f / (float)NS;
        const float gmean    = S[0] * invS;
        const float variance = fmaxf(S[1] * invS - gmean * gmean, 0.f);  // biased
        const float mean_abs = S[2] * invS;
        const float missing  = S[3] * invS;
        const float max_abs  = S[4];
        float between = 0.f;
        #pragma unroll
        for (int c = 0; c < NC; c++) {
            const float cnt = (float)counts_i[b * NC + c];
            const float cm  = S[5 + c] / fmaxf(cnt, 1.f);
            const float d   = cm - gmean;
            between = fmaf(cnt * d, d, between);
        }
        between *= invS;                                   // counts.sum() == NS
        const float target = between / fmaxf(variance, 1e-6f);
        float st6[6] = { target, missing, u * invS, variance, mean_abs, max_abs };
        #pragma unroll
        for (int i = 0; i < 6; i++) {
            float v = st6[i];
            if (!(fabsf(v) < INFINITY)) v = 0.f;           // nan_to_num
            stats_s[i] = v;
        }
    }
    __syncthreads();

    // MLP epilogue: 6 -> 64 (exact GELU) -> 128
    if (tid < 64) {
        float z = b1[tid];
        #pragma unroll
        for (int i = 0; i < 6; i++) z = fmaf(stats_s[i], w1[i * 64 + tid], z);
        h_s[tid] = 0.5f * z * (1.f + erff(z * 0.70710678118654752440f));
    }
    __syncthreads();
    if (tid < 128) {
        float o = b2[tid];
        #pragma unroll
        for (int j = 0; j < 64; j++) o = fmaf(h_s[j], w2[j * 128 + tid], o);
        out[(size_t)g * 128 + tid] = o;
    }
}

// ---------------- fallback path (round-0 proven, strided) ----------------
__global__ void count_classes_kernel(const int* __restrict__ y, float* __restrict__ counts) {
    __shared__ int hist[NC];
    const int b = blockIdx.x;
    if (threadIdx.x < NC) hist[threadIdx.x] = 0;
    __syncthreads();
    for (int s = threadIdx.x; s < NS; s += blockDim.x)
        atomicAdd(&hist[y[b * NS + s]], 1);
    __syncthreads();
    if (threadIdx.x < NC) counts[b * NC + threadIdx.x] = (float)hist[threadIdx.x];
}

__device__ __forceinline__ float wave_reduce_add64(float v) {
    #pragma unroll
    for (int off = 32; off > 0; off >>= 1) v += __shfl_down(v, off, 64);
    return v;
}
__device__ __forceinline__ float wave_reduce_max64(float v) {
    #pragma unroll
    for (int off = 32; off > 0; off >>= 1) v = fmaxf(v, __shfl_down(v, off, 64));
    return v;
}

__launch_bounds__(256)
__global__ void fused_stats_mlp_kernel(const float* __restrict__ X,
                                       const int* __restrict__ y,
                                       const float* __restrict__ counts,
                                       const float* __restrict__ w1,
                                       const float* __restrict__ b1,
                                       const float* __restrict__ w2,
                                       const float* __restrict__ b2,
                                       float* __restrict__ out) {
    __shared__ unsigned int hash[HSIZE];
    __shared__ float red[4][16];
    __shared__ float stats_s[6];
    __shared__ float h_s[64];

    const int w = blockIdx.x;
    const int g = (w & 7) * 1024 + (w >> 3);
    const int b = g >> 9;
    const int f = g & (NF - 1);
    const int tid = threadIdx.x;

    #pragma unroll
    for (int i = 0; i < HSIZE / 256; i++) hash[tid + i * 256] = HEMPTY;
    __syncthreads();

    const float* Xp = X + (size_t)b * NS * NF + f;
    const int*   yp = y + b * NS;

    float sum = 0.f, sumsq = 0.f, sumabs = 0.f, maxabs = 0.f, nancnt = 0.f, uniq = 0.f;
    float csum[NC];
    #pragma unroll
    for (int c = 0; c < NC; c++) csum[c] = 0.f;

    #pragma unroll
    for (int k0 = 0; k0 < 16; k0 += 8) {
        float xv[8]; int yv[8];
        #pragma unroll
        for (int k = 0; k < 8; k++) {
            const int s = (k0 + k) * 256 + tid;
            xv[k] = Xp[(size_t)s * NF];
            yv[k] = yp[s];
        }
        #pragma unroll
        for (int k = 0; k < 8; k++) {
            float x = xv[k];
            if (x != x) { nancnt += 1.f; x = 0.f; }
            sum += x;
            sumsq = fmaf(x, x, sumsq);
            const float a = fabsf(x);
            sumabs += a;
            maxabs = fmaxf(maxabs, a);
            const int yc = yv[k];
            #pragma unroll
            for (int c = 0; c < NC; c++) csum[c] += (yc == c) ? x : 0.f;
            unsigned int pat = __float_as_uint(x);
            if (pat == 0x80000000u) pat = 0u;
            unsigned int slot = (pat * 2654435761u) >> 19;
            for (;;) {
                const unsigned int old = atomicCAS(&hash[slot], HEMPTY, pat);
                if (old == HEMPTY) { uniq += 1.f; break; }
                if (old == pat) break;
                slot = (slot + 1) & HMASK;
            }
        }
    }

    sum    = wave_reduce_add64(sum);
    sumsq  = wave_reduce_add64(sumsq);
    sumabs = wave_reduce_add64(sumabs);
    nancnt = wave_reduce_add64(nancnt);
    uniq   = wave_reduce_add64(uniq);
    maxabs = wave_reduce_max64(maxabs);
    #pragma unroll
    for (int c = 0; c < NC; c++) csum[c] = wave_reduce_add64(csum[c]);

    const int wave = tid >> 6, lane = tid & 63;
    if (lane == 0) {
        red[wave][0] = sum;    red[wave][1] = sumsq; red[wave][2] = sumabs;
        red[wave][3] = nancnt; red[wave][4] = uniq;  red[wave][5] = maxabs;
        #pragma unroll
        for (int c = 0; c < NC; c++) red[wave][6 + c] = csum[c];
    }
    __syncthreads();

    if (tid == 0) {
        float t[16];
        #pragma unroll
        for (int v = 0; v < 16; v++) t[v] = red[0][v];
        #pragma unroll
        for (int wv = 1; wv < 4; wv++) {
            #pragma unroll
            for (int v = 0; v < 16; v++) {
                if (v == 5) t[v] = fmaxf(t[v], red[wv][v]);
                else        t[v] += red[wv][v];
            }
        }
        const float invS = 1.f / (float)NS;
        const float gmean    = t[0] * invS;
        const float variance = fmaxf(t[1] * invS - gmean * gmean, 0.f);
        const float mean_abs = t[2] * invS;
        const float missing  = t[3] * invS;
        const float n_unique = t[4];
        const float max_abs  = t[5];
        float between = 0.f;
        #pragma unroll
        for (int c = 0; c < NC; c++) {
            const float cnt = counts[b * NC + c];
            const float cm  = t[6 + c] / fmaxf(cnt, 1.f);
            const float d   = cm - gmean;
            between += cnt * d * d;
        }
        between *= invS;
        const float target = between / fmaxf(variance, 1e-6f);
        float st[6] = { target, missing, n_unique * invS, variance, mean_abs, max_abs };
        #pragma unroll
        for (int i = 0; i < 6; i++) {
            float v = st[i];
            if (!(fabsf(v) < INFINITY)) v = 0.f;
            stats_s[i] = v;
        }
    }
    __syncthreads();

    if (tid < 64) {
        float z = b1[tid];
        #pragma unroll
        for (int i = 0; i < 6; i++) z = fmaf(stats_s[i], w1[i * 64 + tid], z);
        h_s[tid] = 0.5f * z * (1.f + erff(z * 0.70710678118654752440f));
    }
    __syncthreads();
    if (tid < 128) {
        float o = b2[tid];
        #pragma unroll
        for (int j = 0; j < 64; j++) o = fmaf(h_s[j], w2[j * 128 + tid], o);
        out[(size_t)g * 128 + tid] = o;
    }
}

extern "C" void kernel_launch(void* const* d_in, const int* in_sizes, int n_in,
                              void* d_out, int out_size, void* d_ws, size_t ws_size,
                              hipStream_t stream) {
    const float* X  = (const float*)d_in[0];
    const int*   y  = (const int*)d_in[1];
    const float* w1 = (const float*)d_in[2];
    const float* b1 = (const float*)d_in[3];
    const float* w2 = (const float*)d_in[4];
    const float* b2 = (const float*)d_in[5];
    float* out = (float*)d_out;

    const size_t xt_bytes = (size_t)NB * NF * NS * sizeof(float);   // 128 MB
    if (ws_size >= (size_t)WS_XT_OFF + xt_bytes) {
        int*   counts_i = (int*)d_ws;                       // NB*NC ints
        float* P2 = (float*)((char*)d_ws + WS_P_OFF);       // [B][F][NSEG][16]
        float* XT = (float*)((char*)d_ws + WS_XT_OFF);
        hipMemsetAsync(d_ws, 0, NB * NC * sizeof(int), stream);
        stripe_stats_kernel<<<dim3(NB, NF / TSC, NSEG), 512, 0, stream>>>(
            X, XT, y, P2, counts_i);
        fused_hash_mlp<<<NB * NF, 512, 0, stream>>>(
            XT, P2, counts_i, w1, b1, w2, b2, out);
    } else {
        // workspace too small: proven strided path (round-0 structure)
        float* counts = (float*)d_ws;
        count_classes_kernel<<<NB, 256, 0, stream>>>(y, counts);
        fused_stats_mlp_kernel<<<NB * NF, 256, 0, stream>>>(X, y, counts, w1, b1, w2, b2, out);
    }
}

// Round 12
// 311.829 us; speedup vs baseline: 1.2466x; 1.0373x over previous
//
#include <hip/hip_runtime.h>
#include <math.h>

#define NS 4096
#define NF 512
#define NB 16
#define NC 10
#define HSIZE 8192
#define HMASK 8191
#define HEMPTY 0xFFFFFFFFu
#define TSR 128                      // stripe tile rows (R10-proven)
#define TSC 16                       // stripe cols
#define NSEG 4                       // segments along S
#define SEGR (NS / NSEG)             // 1024 rows per segment
#define WS_P_OFF  1024
#define P2_BYTES (NB * NF * NSEG * 16 * 4)            // 2 MB
#define WS_XT_OFF (WS_P_OFF + P2_BYTES)               // counts | P2 | XT

// ---------------- helpers ----------------
__device__ __forceinline__ float wave_reduce_add(float v) {
    #pragma unroll
    for (int off = 32; off > 0; off >>= 1) v += __shfl_down(v, off, 64);
    return v;
}

__device__ __forceinline__ unsigned int pat_of(float x) {
    if (x != x) x = 0.f;                       // nan_to_num for the hash
    unsigned int p = __float_as_uint(x);
    return (p == 0x80000000u) ? 0u : p;        // -0.0 == +0.0 value semantics
}

// ---------------- kernel S: segmented stripe transpose + moment stats --------------
// R10-PROVEN VERSION (verbatim). one 512-thread block per (b, stripe, segment).
__launch_bounds__(512, 4)
__global__ void stripe_stats_kernel(const float* __restrict__ X,
                                    float* __restrict__ XT,
                                    const int* __restrict__ y,
                                    float* __restrict__ P2,
                                    int* __restrict__ counts_i) {
    __shared__ float t[TSR][TSC + 1];
    __shared__ int ys[TSR];
    __shared__ int hist[NC];
    const int b   = blockIdx.x;
    const int f0  = blockIdx.y * TSC;
    const int seg = blockIdx.z;
    const int tid = threadIdx.x;
    const bool do_hist = (blockIdx.y == 0);
    if (do_hist && tid < NC) hist[tid] = 0;    // ordered before use by iter-0 syncs

    const int lrow = tid >> 2, lq = tid & 3;   // load mapping: 128 rows x 4 quads
    const int col  = tid >> 5, rq = tid & 31;  // stats mapping: 16 cols x 32 lanes

    const int sbase = seg * SEGR;
    const float* Xb = X + (size_t)b * NS * NF + f0 + lq * 4;
    const int*   yb = y + (size_t)b * NS;

    float sum = 0.f, sumsq = 0.f, sumabs = 0.f, maxabs = 0.f, nancnt = 0.f;
    float csum[NC];
    #pragma unroll
    for (int c = 0; c < NC; c++) csum[c] = 0.f;

    // software pipeline: load tile k+1 while processing tile k
    float4 xcur = *(const float4*)(Xb + (size_t)(sbase + lrow) * NF);
    int4 ycur = make_int4(0, 0, 0, 0);
    if (tid < TSR / 4) ycur = *(const int4*)(yb + sbase + tid * 4);

    for (int it = 0; it < SEGR / TSR; ++it) {  // 8 tiles per segment
        const int s0 = sbase + it * TSR;
        float4 xnext = xcur; int4 ynext = ycur;
        if (it + 1 < SEGR / TSR) {
            xnext = *(const float4*)(Xb + (size_t)(s0 + TSR + lrow) * NF);
            if (tid < TSR / 4) ynext = *(const int4*)(yb + s0 + TSR + tid * 4);
        }
        __syncthreads();                       // prior tile's LDS reads complete
        t[lrow][lq * 4 + 0] = xcur.x; t[lrow][lq * 4 + 1] = xcur.y;
        t[lrow][lq * 4 + 2] = xcur.z; t[lrow][lq * 4 + 3] = xcur.w;
        if (tid < TSR / 4) {
            ys[tid * 4 + 0] = ycur.x; ys[tid * 4 + 1] = ycur.y;
            ys[tid * 4 + 2] = ycur.z; ys[tid * 4 + 3] = ycur.w;
        }
        __syncthreads();                       // tile ready
        if (do_hist && tid < TSR) atomicAdd(&hist[ys[tid]], 1);

        #pragma unroll
        for (int j = 0; j < 4; j++) {          // rows rq+32j: conflict-free reads
            const int r = rq + 32 * j;
            float x = t[r][col];
            const int yc = ys[r];
            if (x != x) { nancnt += 1.f; x = 0.f; }          // nan_to_num
            sum += x;
            sumsq = fmaf(x, x, sumsq);
            const float a = fabsf(x);
            sumabs += a;
            maxabs = fmaxf(maxabs, a);
            #pragma unroll
            for (int c = 0; c < NC; c++) csum[c] += (yc == c) ? x : 0.f;
        }
        // XT write: RAW values (hash does its own nan/-0 normalization)
        float4 wv;
        wv.x = t[rq * 4 + 0][col]; wv.y = t[rq * 4 + 1][col];
        wv.z = t[rq * 4 + 2][col]; wv.w = t[rq * 4 + 3][col];
        *(float4*)(XT + ((size_t)b * NF + f0 + col) * NS + s0 + rq * 4) = wv;

        xcur = xnext; ycur = ynext;
    }

    // per-segment partials: width-32 shfl reduce, lane rq==0 stores 15 stats
    float st[15] = { sum, sumsq, sumabs, nancnt, maxabs,
                     csum[0], csum[1], csum[2], csum[3], csum[4],
                     csum[5], csum[6], csum[7], csum[8], csum[9] };
    #pragma unroll
    for (int s = 0; s < 15; s++) {
        float v = st[s];
        #pragma unroll
        for (int off = 16; off > 0; off >>= 1) {
            const float o = __shfl_down(v, off, 32);
            v = (s == 4) ? fmaxf(v, o) : v + o;
        }
        if (rq == 0)
            P2[(((size_t)b * NF + f0 + col) * NSEG + seg) * 16 + s] = v;
    }
    if (do_hist) {
        __syncthreads();                       // all hist atomics done
        if (tid < NC) atomicAdd(&counts_i[b * NC + tid], hist[tid]);
    }
}

// ---------------- kernel 2: WRITE-AND-VERIFY hash-unique + finalize + MLP ---------
// ONLY change vs R10 (two-lane discipline: stripe reverted to proven version).
// 512 threads per (b,f) column, 8 elem/thread. NO ATOMICS: per round each
// unsettled element (1) plain-writes its pattern to its probe slot, (2) reads
// back (match => my value stuck), (3) matched write a per-element NaN-space tag
// 0x7FC00000|(tid*8+e) (data can never be a NaN pattern: NaN->0), (4) read tag
// -> exactly one element per distinct value counts. Losers advance by a
// per-value odd step (double hashing). Same-value elements move in lockstep
// (slot/step are pure functions of the value) => each value counted once.
// Replaces per-lane dependent atomicCAS chains (~130cyc LDS round-trips) with
// round-batched throughput DS ops + 4 barriers/round (~6-8 rounds).
__launch_bounds__(512, 8)
__global__ void fused_hash_mlp(const float* __restrict__ XT,
                               const float* __restrict__ P2,
                               const int* __restrict__ counts_i,
                               const float* __restrict__ w1,
                               const float* __restrict__ b1,
                               const float* __restrict__ w2,
                               const float* __restrict__ b2,
                               float* __restrict__ out) {
    __shared__ __align__(16) unsigned int T[HSIZE];   // 32 KB, multi-purpose
    __shared__ int anyflag;

    const int w = blockIdx.x;
    const int g = (w & 7) * 1024 + (w >> 3);   // XCD swizzle, bijection over [0,8192)
    const int b = g >> 9;
    const int f = g & (NF - 1);
    const int tid = threadIdx.x;
    const int wave = tid >> 6, lane = tid & 63;

    // prefetch BEFORE init: loads in flight while the table is cleared
    const float4* Xc4 = (const float4*)(XT + ((size_t)b * NF + f) * NS);
    const float4 xa = Xc4[tid];
    const float4 xb = Xc4[512 + tid];

    uint4* h4 = (uint4*)T;
    const uint4 e4 = make_uint4(HEMPTY, HEMPTY, HEMPTY, HEMPTY);
    #pragma unroll
    for (int i = 0; i < HSIZE / 4 / 512; i++) h4[i * 512 + tid] = e4;
    __syncthreads();

    unsigned int pat[8] = { pat_of(xa.x), pat_of(xa.y), pat_of(xa.z), pat_of(xa.w),
                            pat_of(xb.x), pat_of(xb.y), pat_of(xb.z), pat_of(xb.w) };
    unsigned int slot[8];
    #pragma unroll
    for (int e = 0; e < 8; e++) slot[e] = (pat[e] * 2654435761u) >> 19;

    float uniq = 0.f;
    int uns = 0xFF;
    for (;;) {
        #pragma unroll
        for (int e = 0; e < 8; e++)            // phase 1: batched val writes
            if (uns & (1 << e)) T[slot[e]] = pat[e];
        __syncthreads();
        int matched = 0;
        #pragma unroll
        for (int e = 0; e < 8; e++)            // phase 2: batched verify reads
            if (uns & (1 << e)) matched |= (T[slot[e]] == pat[e]) ? (1 << e) : 0;
        __syncthreads();
        if (tid == 0) anyflag = 0;             // ordered: bar2 < here < bar3
        #pragma unroll
        for (int e = 0; e < 8; e++)            // phase 3: tag race (same-value only)
            if (matched & (1 << e)) T[slot[e]] = 0x7FC00000u | (unsigned)(tid * 8 + e);
        __syncthreads();
        #pragma unroll
        for (int e = 0; e < 8; e++)            // phase 4: tag winner counts
            if (matched & (1 << e))
                uniq += (T[slot[e]] == (0x7FC00000u | (unsigned)(tid * 8 + e))) ? 1.f : 0.f;
        uns &= ~matched;
        #pragma unroll
        for (int e = 0; e < 8; e++)            // losers: per-value odd step (dbl hash)
            if (uns & (1 << e))
                slot[e] = (slot[e] + ((pat[e] & 0x1FFFu) | 1u)) & HMASK;
        if (uns) anyflag = 1;                  // after bar3 > tid0's 0-write
        __syncthreads();
        if (!anyflag) break;                   // uniform exit
    }

    // -------- reduce uniq + finalize + MLP (T region re-aliased) -----------------
    float* r = (float*)T;                      // [0,8): wave uniq partials
    float* stats_s = r + 32;                   // [32,38)
    float* h_s = r + 64;                       // [64,128)

    uniq = wave_reduce_add(uniq);
    if (lane == 0) r[wave] = uniq;
    __syncthreads();

    if (tid == 0) {
        float u = 0.f;
        #pragma unroll
        for (int i = 0; i < 8; i++) u += r[i];
        const float* Pp = P2 + ((size_t)b * NF + f) * (NSEG * 16);
        float S[15];
        #pragma unroll
        for (int s = 0; s < 15; s++) {
            float v0 = Pp[s], v1 = Pp[16 + s], v2 = Pp[32 + s], v3 = Pp[48 + s];
            S[s] = (s == 4) ? fmaxf(fmaxf(v0, v1), fmaxf(v2, v3))
                            : (v0 + v1) + (v2 + v3);
        }
        const float invS = 1.f / (float)NS;
        const float gmean    = S[0] * invS;
        const float variance = fmaxf(S[1] * invS - gmean * gmean, 0.f);  // biased
        const float mean_abs = S[2] * invS;
        const float missing  = S[3] * invS;
        const float max_abs  = S[4];
        float between = 0.f;
        #pragma unroll
        for (int c = 0; c < NC; c++) {
            const float cnt = (float)counts_i[b * NC + c];
            const float cm  = S[5 + c] / fmaxf(cnt, 1.f);
            const float d   = cm - gmean;
            between = fmaf(cnt * d, d, between);
        }
        between *= invS;                                   // counts.sum() == NS
        const float target = between / fmaxf(variance, 1e-6f);
        float st6[6] = { target, missing, u * invS, variance, mean_abs, max_abs };
        #pragma unroll
        for (int i = 0; i < 6; i++) {
            float v = st6[i];
            if (!(fabsf(v) < INFINITY)) v = 0.f;           // nan_to_num
            stats_s[i] = v;
        }
    }
    __syncthreads();

    // MLP epilogue: 6 -> 64 (exact GELU) -> 128
    if (tid < 64) {
        float z = b1[tid];
        #pragma unroll
        for (int i = 0; i < 6; i++) z = fmaf(stats_s[i], w1[i * 64 + tid], z);
        h_s[tid] = 0.5f * z * (1.f + erff(z * 0.70710678118654752440f));
    }
    __syncthreads();
    if (tid < 128) {
        float o = b2[tid];
        #pragma unroll
        for (int j = 0; j < 64; j++) o = fmaf(h_s[j], w2[j * 128 + tid], o);
        out[(size_t)g * 128 + tid] = o;
    }
}

// ---------------- fallback path (round-0 proven, strided) ----------------
__global__ void count_classes_kernel(const int* __restrict__ y, float* __restrict__ counts) {
    __shared__ int hist[NC];
    const int b = blockIdx.x;
    if (threadIdx.x < NC) hist[threadIdx.x] = 0;
    __syncthreads();
    for (int s = threadIdx.x; s < NS; s += blockDim.x)
        atomicAdd(&hist[y[b * NS + s]], 1);
    __syncthreads();
    if (threadIdx.x < NC) counts[b * NC + threadIdx.x] = (float)hist[threadIdx.x];
}

__device__ __forceinline__ float wave_reduce_max64(float v) {
    #pragma unroll
    for (int off = 32; off > 0; off >>= 1) v = fmaxf(v, __shfl_down(v, off, 64));
    return v;
}

__launch_bounds__(256)
__global__ void fused_stats_mlp_kernel(const float* __restrict__ X,
                                       const int* __restrict__ y,
                                       const float* __restrict__ counts,
                                       const float* __restrict__ w1,
                                       const float* __restrict__ b1,
                                       const float* __restrict__ w2,
                                       const float* __restrict__ b2,
                                       float* __restrict__ out) {
    __shared__ unsigned int hash[HSIZE];
    __shared__ float red[4][16];
    __shared__ float stats_s[6];
    __shared__ float h_s[64];

    const int w = blockIdx.x;
    const int g = (w & 7) * 1024 + (w >> 3);
    const int b = g >> 9;
    const int f = g & (NF - 1);
    const int tid = threadIdx.x;

    #pragma unroll
    for (int i = 0; i < HSIZE / 256; i++) hash[tid + i * 256] = HEMPTY;
    __syncthreads();

    const float* Xp = X + (size_t)b * NS * NF + f;
    const int*   yp = y + b * NS;

    float sum = 0.f, sumsq = 0.f, sumabs = 0.f, maxabs = 0.f, nancnt = 0.f, uniq = 0.f;
    float csum[NC];
    #pragma unroll
    for (int c = 0; c < NC; c++) csum[c] = 0.f;

    #pragma unroll
    for (int k0 = 0; k0 < 16; k0 += 8) {
        float xv[8]; int yv[8];
        #pragma unroll
        for (int k = 0; k < 8; k++) {
            const int s = (k0 + k) * 256 + tid;
            xv[k] = Xp[(size_t)s * NF];
            yv[k] = yp[s];
        }
        #pragma unroll
        for (int k = 0; k < 8; k++) {
            float x = xv[k];
            if (x != x) { nancnt += 1.f; x = 0.f; }
            sum += x;
            sumsq = fmaf(x, x, sumsq);
            const float a = fabsf(x);
            sumabs += a;
            maxabs = fmaxf(maxabs, a);
            const int yc = yv[k];
            #pragma unroll
            for (int c = 0; c < NC; c++) csum[c] += (yc == c) ? x : 0.f;
            unsigned int pat = __float_as_uint(x);
            if (pat == 0x80000000u) pat = 0u;
            unsigned int slot = (pat * 2654435761u) >> 19;
            for (;;) {
                const unsigned int old = atomicCAS(&hash[slot], HEMPTY, pat);
                if (old == HEMPTY) { uniq += 1.f; break; }
                if (old == pat) break;
                slot = (slot + 1) & HMASK;
            }
        }
    }

    sum    = wave_reduce_add(sum);
    sumsq  = wave_reduce_add(sumsq);
    sumabs = wave_reduce_add(sumabs);
    nancnt = wave_reduce_add(nancnt);
    uniq   = wave_reduce_add(uniq);
    maxabs = wave_reduce_max64(maxabs);
    #pragma unroll
    for (int c = 0; c < NC; c++) csum[c] = wave_reduce_add(csum[c]);

    const int wave = tid >> 6, lane = tid & 63;
    if (lane == 0) {
        red[wave][0] = sum;    red[wave][1] = sumsq; red[wave][2] = sumabs;
        red[wave][3] = nancnt; red[wave][4] = uniq;  red[wave][5] = maxabs;
        #pragma unroll
        for (int c = 0; c < NC; c++) red[wave][6 + c] = csum[c];
    }
    __syncthreads();

    if (tid == 0) {
        float t[16];
        #pragma unroll
        for (int v = 0; v < 16; v++) t[v] = red[0][v];
        #pragma unroll
        for (int wv = 1; wv < 4; wv++) {
            #pragma unroll
            for (int v = 0; v < 16; v++) {
                if (v == 5) t[v] = fmaxf(t[v], red[wv][v]);
                else        t[v] += red[wv][v];
            }
        }
        const float invS = 1.f / (float)NS;
        const float gmean    = t[0] * invS;
        const float variance = fmaxf(t[1] * invS - gmean * gmean, 0.f);
        const float mean_abs = t[2] * invS;
        const float missing  = t[3] * invS;
        const float n_unique = t[4];
        const float max_abs  = t[5];
        float between = 0.f;
        #pragma unroll
        for (int c = 0; c < NC; c++) {
            const float cnt = counts[b * NC + c];
            const float cm  = t[6 + c] / fmaxf(cnt, 1.f);
            const float d   = cm - gmean;
            between += cnt * d * d;
        }
        between *= invS;
        const float target = between / fmaxf(variance, 1e-6f);
        float st[6] = { target, missing, n_unique * invS, variance, mean_abs, max_abs };
        #pragma unroll
        for (int i = 0; i < 6; i++) {
            float v = st[i];
            if (!(fabsf(v) < INFINITY)) v = 0.f;
            stats_s[i] = v;
        }
    }
    __syncthreads();

    if (tid < 64) {
        float z = b1[tid];
        #pragma unroll
        for (int i = 0; i < 6; i++) z = fmaf(stats_s[i], w1[i * 64 + tid], z);
        h_s[tid] = 0.5f * z * (1.f + erff(z * 0.70710678118654752440f));
    }
    __syncthreads();
    if (tid < 128) {
        float o = b2[tid];
        #pragma unroll
        for (int j = 0; j < 64; j++) o = fmaf(h_s[j], w2[j * 128 + tid], o);
        out[(size_t)g * 128 + tid] = o;
    }
}

extern "C" void kernel_launch(void* const* d_in, const int* in_sizes, int n_in,
                              void* d_out, int out_size, void* d_ws, size_t ws_size,
                              hipStream_t stream) {
    const float* X  = (const float*)d_in[0];
    const int*   y  = (const int*)d_in[1];
    const float* w1 = (const float*)d_in[2];
    const float* b1 = (const float*)d_in[3];
    const float* w2 = (const float*)d_in[4];
    const float* b2 = (const float*)d_in[5];
    float* out = (float*)d_out;

    const size_t xt_bytes = (size_t)NB * NF * NS * sizeof(float);   // 128 MB
    if (ws_size >= (size_t)WS_XT_OFF + xt_bytes) {
        int*   counts_i = (int*)d_ws;                       // NB*NC ints
        float* P2 = (float*)((char*)d_ws + WS_P_OFF);       // [B][F][NSEG][16]
        float* XT = (float*)((char*)d_ws + WS_XT_OFF);
        hipMemsetAsync(d_ws, 0, NB * NC * sizeof(int), stream);
        stripe_stats_kernel<<<dim3(NB, NF / TSC, NSEG), 512, 0, stream>>>(
            X, XT, y, P2, counts_i);
        fused_hash_mlp<<<NB * NF, 512, 0, stream>>>(
            XT, P2, counts_i, w1, b1, w2, b2, out);
    } else {
        // workspace too small: proven strided path (round-0 structure)
        float* counts = (float*)d_ws;
        count_classes_kernel<<<NB, 256, 0, stream>>>(y, counts);
        fused_stats_mlp_kernel<<<NB * NF, 256, 0, stream>>>(X, y, counts, w1, b1, w2, b2, out);
    }
}

// Round 13
// 311.473 us; speedup vs baseline: 1.2481x; 1.0011x over previous
//
#include <hip/hip_runtime.h>
#include <math.h>

#define NS 4096
#define NF 512
#define NB 16
#define NC 10
#define HSIZE 8192
#define HMASK 8191
#define HEMPTY 0xFFFFFFFFu
#define TSR 128                      // stripe tile rows
#define TSC 16                       // stripe cols
#define NSEG 4                       // segments along S
#define SEGR (NS / NSEG)             // 1024 rows per segment
#define WS_P_OFF  1024
#define P2_BYTES (NB * NF * NSEG * 16 * 4)            // 2 MB
#define WS_XT_OFF (WS_P_OFF + P2_BYTES)               // counts | P2 | XT

// ---------------- helpers ----------------
__device__ __forceinline__ float wave_reduce_add(float v) {
    #pragma unroll
    for (int off = 32; off > 0; off >>= 1) v += __shfl_down(v, off, 64);
    return v;
}

__device__ __forceinline__ unsigned int pat_of(float x) {
    if (x != x) x = 0.f;                       // nan_to_num for the hash
    unsigned int p = __float_as_uint(x);
    return (p == 0x80000000u) ? 0u : p;        // -0.0 == +0.0 value semantics
}

// ---------------- kernel S: segmented stripe transpose + moment stats --------------
// R13 re-timing (only kernel changed this round):
//  * double-buffered LDS tiles -> ONE barrier per tile (was 2; m233: 2-phase
//    stage+barrier overhead dominates such loops)
//  * XT written as per-row dword scatter (rows rq+32j, 128B/wave contiguous per
//    store) so the SAME conflict-free LDS read t[cur][rq+32j][col] feeds both
//    stats and XT -> the 4-way-conflicted float4-pack reads are gone entirely.
__launch_bounds__(512, 4)
__global__ void stripe_stats_kernel(const float* __restrict__ X,
                                    float* __restrict__ XT,
                                    const int* __restrict__ y,
                                    float* __restrict__ P2,
                                    int* __restrict__ counts_i) {
    __shared__ float t[2][TSR][TSC + 1];       // 2 x 8.7 KB, bank-safe pad 17
    __shared__ int ys[2][TSR];
    __shared__ int hist[NC];
    const int b   = blockIdx.x;
    const int f0  = blockIdx.y * TSC;
    const int seg = blockIdx.z;
    const int tid = threadIdx.x;
    const bool do_hist = (blockIdx.y == 0);
    if (do_hist && tid < NC) hist[tid] = 0;    // ordered before use by first barrier

    const int lrow = tid >> 2, lq = tid & 3;   // load mapping: 128 rows x 4 quads
    const int col  = tid >> 5, rq = tid & 31;  // stats mapping: 16 cols x 32 lanes

    const int sbase = seg * SEGR;
    const float* Xb = X + (size_t)b * NS * NF + f0 + lq * 4;
    const int*   yb = y + (size_t)b * NS;
    float* XTc = XT + ((size_t)b * NF + f0 + col) * NS;   // this thread's column

    float sum = 0.f, sumsq = 0.f, sumabs = 0.f, maxabs = 0.f, nancnt = 0.f;
    float csum[NC];
    #pragma unroll
    for (int c = 0; c < NC; c++) csum[c] = 0.f;

    // prologue: load tile 0 and stage into buf 0 (no barrier yet; first loop
    // barrier publishes it)
    {
        const float4 xc = *(const float4*)(Xb + (size_t)(sbase + lrow) * NF);
        t[0][lrow][lq * 4 + 0] = xc.x; t[0][lrow][lq * 4 + 1] = xc.y;
        t[0][lrow][lq * 4 + 2] = xc.z; t[0][lrow][lq * 4 + 3] = xc.w;
        if (tid < TSR / 4) {
            const int4 y4 = *(const int4*)(yb + sbase + tid * 4);
            ys[0][tid * 4 + 0] = y4.x; ys[0][tid * 4 + 1] = y4.y;
            ys[0][tid * 4 + 2] = y4.z; ys[0][tid * 4 + 3] = y4.w;
        }
    }

    for (int it = 0; it < SEGR / TSR; ++it) {  // 8 tiles per segment
        const int cur = it & 1;
        const int s0 = sbase + it * TSR;
        const bool more = (it + 1 < SEGR / TSR);
        float4 xn = make_float4(0.f, 0.f, 0.f, 0.f);
        int4 yn4 = make_int4(0, 0, 0, 0);
        if (more) {                            // next-tile loads in flight
            xn = *(const float4*)(Xb + (size_t)(s0 + TSR + lrow) * NF);
            if (tid < TSR / 4) yn4 = *(const int4*)(yb + s0 + TSR + tid * 4);
        }
        __syncthreads();                       // buf[cur] fully staged
        if (do_hist && tid < TSR) atomicAdd(&hist[ys[cur][tid]], 1);

        #pragma unroll
        for (int j = 0; j < 4; j++) {          // rows rq+32j: conflict-free banks
            const int r = rq + 32 * j;
            const float raw = t[cur][r][col];  // ONE read feeds XT + stats
            const int yc = ys[cur][r];
            XTc[s0 + r] = raw;                 // 128B/wave contiguous per j
            float x = raw;
            if (x != x) { nancnt += 1.f; x = 0.f; }          // nan_to_num
            sum += x;
            sumsq = fmaf(x, x, sumsq);
            const float a = fabsf(x);
            sumabs += a;
            maxabs = fmaxf(maxabs, a);
            #pragma unroll
            for (int c = 0; c < NC; c++) csum[c] += (yc == c) ? x : 0.f;
        }
        if (more) {                            // stage NEXT tile into other buf:
            const int nb = cur ^ 1;            // safe, nobody reads it till next bar
            t[nb][lrow][lq * 4 + 0] = xn.x; t[nb][lrow][lq * 4 + 1] = xn.y;
            t[nb][lrow][lq * 4 + 2] = xn.z; t[nb][lrow][lq * 4 + 3] = xn.w;
            if (tid < TSR / 4) {
                ys[nb][tid * 4 + 0] = yn4.x; ys[nb][tid * 4 + 1] = yn4.y;
                ys[nb][tid * 4 + 2] = yn4.z; ys[nb][tid * 4 + 3] = yn4.w;
            }
        }
    }

    // per-segment partials: width-32 shfl reduce, lane rq==0 stores 15 stats
    float st[15] = { sum, sumsq, sumabs, nancnt, maxabs,
                     csum[0], csum[1], csum[2], csum[3], csum[4],
                     csum[5], csum[6], csum[7], csum[8], csum[9] };
    #pragma unroll
    for (int s = 0; s < 15; s++) {
        float v = st[s];
        #pragma unroll
        for (int off = 16; off > 0; off >>= 1) {
            const float o = __shfl_down(v, off, 32);
            v = (s == 4) ? fmaxf(v, o) : v + o;
        }
        if (rq == 0)
            P2[(((size_t)b * NF + f0 + col) * NSEG + seg) * 16 + s] = v;
    }
    if (do_hist) {
        __syncthreads();                       // all hist atomics done
        if (tid < NC) atomicAdd(&counts_i[b * NC + tid], hist[tid]);
    }
}

// ---------------- kernel 2: WRITE-AND-VERIFY hash-unique + finalize + MLP ---------
// R12-PROVEN VERSION (verbatim). 512 threads per (b,f) column, 8 elem/thread.
__launch_bounds__(512, 8)
__global__ void fused_hash_mlp(const float* __restrict__ XT,
                               const float* __restrict__ P2,
                               const int* __restrict__ counts_i,
                               const float* __restrict__ w1,
                               const float* __restrict__ b1,
                               const float* __restrict__ w2,
                               const float* __restrict__ b2,
                               float* __restrict__ out) {
    __shared__ __align__(16) unsigned int T[HSIZE];   // 32 KB, multi-purpose
    __shared__ int anyflag;

    const int w = blockIdx.x;
    const int g = (w & 7) * 1024 + (w >> 3);   // XCD swizzle, bijection over [0,8192)
    const int b = g >> 9;
    const int f = g & (NF - 1);
    const int tid = threadIdx.x;
    const int wave = tid >> 6, lane = tid & 63;

    // prefetch BEFORE init: loads in flight while the table is cleared
    const float4* Xc4 = (const float4*)(XT + ((size_t)b * NF + f) * NS);
    const float4 xa = Xc4[tid];
    const float4 xb = Xc4[512 + tid];

    uint4* h4 = (uint4*)T;
    const uint4 e4 = make_uint4(HEMPTY, HEMPTY, HEMPTY, HEMPTY);
    #pragma unroll
    for (int i = 0; i < HSIZE / 4 / 512; i++) h4[i * 512 + tid] = e4;
    __syncthreads();

    unsigned int pat[8] = { pat_of(xa.x), pat_of(xa.y), pat_of(xa.z), pat_of(xa.w),
                            pat_of(xb.x), pat_of(xb.y), pat_of(xb.z), pat_of(xb.w) };
    unsigned int slot[8];
    #pragma unroll
    for (int e = 0; e < 8; e++) slot[e] = (pat[e] * 2654435761u) >> 19;

    float uniq = 0.f;
    int uns = 0xFF;
    for (;;) {
        #pragma unroll
        for (int e = 0; e < 8; e++)            // phase 1: batched val writes
            if (uns & (1 << e)) T[slot[e]] = pat[e];
        __syncthreads();
        int matched = 0;
        #pragma unroll
        for (int e = 0; e < 8; e++)            // phase 2: batched verify reads
            if (uns & (1 << e)) matched |= (T[slot[e]] == pat[e]) ? (1 << e) : 0;
        __syncthreads();
        if (tid == 0) anyflag = 0;             // ordered: bar2 < here < bar3
        #pragma unroll
        for (int e = 0; e < 8; e++)            // phase 3: tag race (same-value only)
            if (matched & (1 << e)) T[slot[e]] = 0x7FC00000u | (unsigned)(tid * 8 + e);
        __syncthreads();
        #pragma unroll
        for (int e = 0; e < 8; e++)            // phase 4: tag winner counts
            if (matched & (1 << e))
                uniq += (T[slot[e]] == (0x7FC00000u | (unsigned)(tid * 8 + e))) ? 1.f : 0.f;
        uns &= ~matched;
        #pragma unroll
        for (int e = 0; e < 8; e++)            // losers: per-value odd step (dbl hash)
            if (uns & (1 << e))
                slot[e] = (slot[e] + ((pat[e] & 0x1FFFu) | 1u)) & HMASK;
        if (uns) anyflag = 1;                  // after bar3 > tid0's 0-write
        __syncthreads();
        if (!anyflag) break;                   // uniform exit
    }

    // -------- reduce uniq + finalize + MLP (T region re-aliased) -----------------
    float* r = (float*)T;                      // [0,8): wave uniq partials
    float* stats_s = r + 32;                   // [32,38)
    float* h_s = r + 64;                       // [64,128)

    uniq = wave_reduce_add(uniq);
    if (lane == 0) r[wave] = uniq;
    __syncthreads();

    if (tid == 0) {
        float u = 0.f;
        #pragma unroll
        for (int i = 0; i < 8; i++) u += r[i];
        const float* Pp = P2 + ((size_t)b * NF + f) * (NSEG * 16);
        float S[15];
        #pragma unroll
        for (int s = 0; s < 15; s++) {
            float v0 = Pp[s], v1 = Pp[16 + s], v2 = Pp[32 + s], v3 = Pp[48 + s];
            S[s] = (s == 4) ? fmaxf(fmaxf(v0, v1), fmaxf(v2, v3))
                            : (v0 + v1) + (v2 + v3);
        }
        const float invS = 1.f / (float)NS;
        const float gmean    = S[0] * invS;
        const float variance = fmaxf(S[1] * invS - gmean * gmean, 0.f);  // biased
        const float mean_abs = S[2] * invS;
        const float missing  = S[3] * invS;
        const float max_abs  = S[4];
        float between = 0.f;
        #pragma unroll
        for (int c = 0; c < NC; c++) {
            const float cnt = (float)counts_i[b * NC + c];
            const float cm  = S[5 + c] / fmaxf(cnt, 1.f);
            const float d   = cm - gmean;
            between = fmaf(cnt * d, d, between);
        }
        between *= invS;                                   // counts.sum() == NS
        const float target = between / fmaxf(variance, 1e-6f);
        float st6[6] = { target, missing, u * invS, variance, mean_abs, max_abs };
        #pragma unroll
        for (int i = 0; i < 6; i++) {
            float v = st6[i];
            if (!(fabsf(v) < INFINITY)) v = 0.f;           // nan_to_num
            stats_s[i] = v;
        }
    }
    __syncthreads();

    // MLP epilogue: 6 -> 64 (exact GELU) -> 128
    if (tid < 64) {
        float z = b1[tid];
        #pragma unroll
        for (int i = 0; i < 6; i++) z = fmaf(stats_s[i], w1[i * 64 + tid], z);
        h_s[tid] = 0.5f * z * (1.f + erff(z * 0.70710678118654752440f));
    }
    __syncthreads();
    if (tid < 128) {
        float o = b2[tid];
        #pragma unroll
        for (int j = 0; j < 64; j++) o = fmaf(h_s[j], w2[j * 128 + tid], o);
        out[(size_t)g * 128 + tid] = o;
    }
}

// ---------------- fallback path (round-0 proven, strided) ----------------
__global__ void count_classes_kernel(const int* __restrict__ y, float* __restrict__ counts) {
    __shared__ int hist[NC];
    const int b = blockIdx.x;
    if (threadIdx.x < NC) hist[threadIdx.x] = 0;
    __syncthreads();
    for (int s = threadIdx.x; s < NS; s += blockDim.x)
        atomicAdd(&hist[y[b * NS + s]], 1);
    __syncthreads();
    if (threadIdx.x < NC) counts[b * NC + threadIdx.x] = (float)hist[threadIdx.x];
}

__device__ __forceinline__ float wave_reduce_max64(float v) {
    #pragma unroll
    for (int off = 32; off > 0; off >>= 1) v = fmaxf(v, __shfl_down(v, off, 64));
    return v;
}

__launch_bounds__(256)
__global__ void fused_stats_mlp_kernel(const float* __restrict__ X,
                                       const int* __restrict__ y,
                                       const float* __restrict__ counts,
                                       const float* __restrict__ w1,
                                       const float* __restrict__ b1,
                                       const float* __restrict__ w2,
                                       const float* __restrict__ b2,
                                       float* __restrict__ out) {
    __shared__ unsigned int hash[HSIZE];
    __shared__ float red[4][16];
    __shared__ float stats_s[6];
    __shared__ float h_s[64];

    const int w = blockIdx.x;
    const int g = (w & 7) * 1024 + (w >> 3);
    const int b = g >> 9;
    const int f = g & (NF - 1);
    const int tid = threadIdx.x;

    #pragma unroll
    for (int i = 0; i < HSIZE / 256; i++) hash[tid + i * 256] = HEMPTY;
    __syncthreads();

    const float* Xp = X + (size_t)b * NS * NF + f;
    const int*   yp = y + b * NS;

    float sum = 0.f, sumsq = 0.f, sumabs = 0.f, maxabs = 0.f, nancnt = 0.f, uniq = 0.f;
    float csum[NC];
    #pragma unroll
    for (int c = 0; c < NC; c++) csum[c] = 0.f;

    #pragma unroll
    for (int k0 = 0; k0 < 16; k0 += 8) {
        float xv[8]; int yv[8];
        #pragma unroll
        for (int k = 0; k < 8; k++) {
            const int s = (k0 + k) * 256 + tid;
            xv[k] = Xp[(size_t)s * NF];
            yv[k] = yp[s];
        }
        #pragma unroll
        for (int k = 0; k < 8; k++) {
            float x = xv[k];
            if (x != x) { nancnt += 1.f; x = 0.f; }
            sum += x;
            sumsq = fmaf(x, x, sumsq);
            const float a = fabsf(x);
            sumabs += a;
            maxabs = fmaxf(maxabs, a);
            const int yc = yv[k];
            #pragma unroll
            for (int c = 0; c < NC; c++) csum[c] += (yc == c) ? x : 0.f;
            unsigned int pat = __float_as_uint(x);
            if (pat == 0x80000000u) pat = 0u;
            unsigned int slot = (pat * 2654435761u) >> 19;
            for (;;) {
                const unsigned int old = atomicCAS(&hash[slot], HEMPTY, pat);
                if (old == HEMPTY) { uniq += 1.f; break; }
                if (old == pat) break;
                slot = (slot + 1) & HMASK;
            }
        }
    }

    sum    = wave_reduce_add(sum);
    sumsq  = wave_reduce_add(sumsq);
    sumabs = wave_reduce_add(sumabs);
    nancnt = wave_reduce_add(nancnt);
    uniq   = wave_reduce_add(uniq);
    maxabs = wave_reduce_max64(maxabs);
    #pragma unroll
    for (int c = 0; c < NC; c++) csum[c] = wave_reduce_add(csum[c]);

    const int wave = tid >> 6, lane = tid & 63;
    if (lane == 0) {
        red[wave][0] = sum;    red[wave][1] = sumsq; red[wave][2] = sumabs;
        red[wave][3] = nancnt; red[wave][4] = uniq;  red[wave][5] = maxabs;
        #pragma unroll
        for (int c = 0; c < NC; c++) red[wave][6 + c] = csum[c];
    }
    __syncthreads();

    if (tid == 0) {
        float t[16];
        #pragma unroll
        for (int v = 0; v < 16; v++) t[v] = red[0][v];
        #pragma unroll
        for (int wv = 1; wv < 4; wv++) {
            #pragma unroll
            for (int v = 0; v < 16; v++) {
                if (v == 5) t[v] = fmaxf(t[v], red[wv][v]);
                else        t[v] += red[wv][v];
            }
        }
        const float invS = 1.f / (float)NS;
        const float gmean    = t[0] * invS;
        const float variance = fmaxf(t[1] * invS - gmean * gmean, 0.f);
        const float mean_abs = t[2] * invS;
        const float missing  = t[3] * invS;
        const float n_unique = t[4];
        const float max_abs  = t[5];
        float between = 0.f;
        #pragma unroll
        for (int c = 0; c < NC; c++) {
            const float cnt = counts[b * NC + c];
            const float cm  = t[6 + c] / fmaxf(cnt, 1.f);
            const float d   = cm - gmean;
            between += cnt * d * d;
        }
        between *= invS;
        const float target = between / fmaxf(variance, 1e-6f);
        float st[6] = { target, missing, n_unique * invS, variance, mean_abs, max_abs };
        #pragma unroll
        for (int i = 0; i < 6; i++) {
            float v = st[i];
            if (!(fabsf(v) < INFINITY)) v = 0.f;
            stats_s[i] = v;
        }
    }
    __syncthreads();

    if (tid < 64) {
        float z = b1[tid];
        #pragma unroll
        for (int i = 0; i < 6; i++) z = fmaf(stats_s[i], w1[i * 64 + tid], z);
        h_s[tid] = 0.5f * z * (1.f + erff(z * 0.70710678118654752440f));
    }
    __syncthreads();
    if (tid < 128) {
        float o = b2[tid];
        #pragma unroll
        for (int j = 0; j < 64; j++) o = fmaf(h_s[j], w2[j * 128 + tid], o);
        out[(size_t)g * 128 + tid] = o;
    }
}

extern "C" void kernel_launch(void* const* d_in, const int* in_sizes, int n_in,
                              void* d_out, int out_size, void* d_ws, size_t ws_size,
                              hipStream_t stream) {
    const float* X  = (const float*)d_in[0];
    const int*   y  = (const int*)d_in[1];
    const float* w1 = (const float*)d_in[2];
    const float* b1 = (const float*)d_in[3];
    const float* w2 = (const float*)d_in[4];
    const float* b2 = (const float*)d_in[5];
    float* out = (float*)d_out;

    const size_t xt_bytes = (size_t)NB * NF * NS * sizeof(float);   // 128 MB
    if (ws_size >= (size_t)WS_XT_OFF + xt_bytes) {
        int*   counts_i = (int*)d_ws;                       // NB*NC ints
        float* P2 = (float*)((char*)d_ws + WS_P_OFF);       // [B][F][NSEG][16]
        float* XT = (float*)((char*)d_ws + WS_XT_OFF);
        hipMemsetAsync(d_ws, 0, NB * NC * sizeof(int), stream);
        stripe_stats_kernel<<<dim3(NB, NF / TSC, NSEG), 512, 0, stream>>>(
            X, XT, y, P2, counts_i);
        fused_hash_mlp<<<NB * NF, 512, 0, stream>>>(
            XT, P2, counts_i, w1, b1, w2, b2, out);
    } else {
        // workspace too small: proven strided path (round-0 structure)
        float* counts = (float*)d_ws;
        count_classes_kernel<<<NB, 256, 0, stream>>>(y, counts);
        fused_stats_mlp_kernel<<<NB * NF, 256, 0, stream>>>(X, y, counts, w1, b1, w2, b2, out);
    }
}